// Round 1
// baseline (12998.538 us; speedup 1.0000x reference)
//
#include <hip/hip_runtime.h>
#include <math.h>

// Problem constants (from reference)
#define S_LEN  1024
#define BATCH  2
#define DMODEL 1024
#define NHEAD  16
#define HDIM   64
#define NLAYER 4
#define MLPD   4096
// rows of the (S,B,D) activation matrix
#define MROWS  (S_LEN*BATCH)   // 2048

// ---------------------------------------------------------------------------
// LayerNorm over last dim (D=1024). One block (256 thr) per row.
// inscale lets us feed a SUM and normalize to a MEAN (pooled query path),
// keeping eps semantics exact.
// ---------------------------------------------------------------------------
__global__ __launch_bounds__(256) void ln_kernel(const float* __restrict__ x,
    const float* __restrict__ w, const float* __restrict__ b,
    float* __restrict__ out, float inscale) {
  const int row = blockIdx.x;
  const int tid = threadIdx.x;
  const float* xr = x + (size_t)row * DMODEL;
  float4 v = *(const float4*)(xr + tid * 4);
  v.x *= inscale; v.y *= inscale; v.z *= inscale; v.w *= inscale;
  float s1 = v.x + v.y + v.z + v.w;
  float s2 = v.x*v.x + v.y*v.y + v.z*v.z + v.w*v.w;
  #pragma unroll
  for (int off = 32; off; off >>= 1) {
    s1 += __shfl_xor(s1, off);
    s2 += __shfl_xor(s2, off);
  }
  __shared__ float as1[4], as2[4];
  if ((tid & 63) == 0) { as1[tid >> 6] = s1; as2[tid >> 6] = s2; }
  __syncthreads();
  s1 = as1[0] + as1[1] + as1[2] + as1[3];
  s2 = as2[0] + as2[1] + as2[2] + as2[3];
  const float mean = s1 * (1.0f / DMODEL);
  const float var  = s2 * (1.0f / DMODEL) - mean * mean;
  const float r = rsqrtf(var + 1e-5f);
  float4 wv = *(const float4*)(w + tid * 4);
  float4 bv = *(const float4*)(b + tid * 4);
  float4 ov;
  ov.x = (v.x - mean) * r * wv.x + bv.x;
  ov.y = (v.y - mean) * r * wv.y + bv.y;
  ov.z = (v.z - mean) * r * wv.z + bv.z;
  ov.w = (v.w - mean) * r * wv.w + bv.w;
  *(float4*)(out + (size_t)row * DMODEL + tid * 4) = ov;
}

// ---------------------------------------------------------------------------
// C[M,N] = A[M,K] * W[N,K]^T (+bias[n]) (+resid) (opt GELU).  fp32.
// BM=128, BK=16, TM=8.  256 threads: 16x16 thread grid, each 8xTN outputs.
// LDS tiles stored k-major so compute reads are ds_read_b128 along m/n.
// All M,N,K used here are multiples of tile dims -> no bounds checks.
// ---------------------------------------------------------------------------
template<int BN, int TN, bool GELU, bool RESID>
__global__ __launch_bounds__(256) void gemm_bt(
    const float* __restrict__ A, const float* __restrict__ W,
    const float* __restrict__ bias, const float* __restrict__ resid,
    float* __restrict__ C, int M, int N, int K) {
  constexpr int BM = 128, BK = 16, TM = 8;
  __shared__ float As[BK][BM];
  __shared__ float Ws[BK][BN];
  const int tid = threadIdx.x;
  const int tx = tid & 15;          // n group
  const int ty = tid >> 4;          // m group
  const int m0 = blockIdx.y * BM;
  const int n0 = blockIdx.x * BN;

  float acc[TM][TN];
  #pragma unroll
  for (int i = 0; i < TM; ++i)
    #pragma unroll
    for (int j = 0; j < TN; ++j) acc[i][j] = 0.f;

  // A staging indices: 128 rows x 16 k = 2048 elems, 8/thread (2x float4)
  const int lm = tid & 127;
  const int lk = (tid >> 7) * 8;
  const float* Ag = A + (size_t)(m0 + lm) * K + lk;
  // W staging indices
  int wn_, wk_;
  if (BN == 128) { wn_ = tid & 127; wk_ = (tid >> 7) * 8; }
  else           { wn_ = tid & 63;  wk_ = (tid >> 6) * 4; }
  const float* Wg = W + (size_t)(n0 + wn_) * K + wk_;

  for (int k0 = 0; k0 < K; k0 += BK) {
    float4 a0 = *(const float4*)(Ag + k0);
    float4 a1 = *(const float4*)(Ag + k0 + 4);
    As[lk + 0][lm] = a0.x; As[lk + 1][lm] = a0.y;
    As[lk + 2][lm] = a0.z; As[lk + 3][lm] = a0.w;
    As[lk + 4][lm] = a1.x; As[lk + 5][lm] = a1.y;
    As[lk + 6][lm] = a1.z; As[lk + 7][lm] = a1.w;
    if (BN == 128) {
      float4 w0 = *(const float4*)(Wg + k0);
      float4 w1 = *(const float4*)(Wg + k0 + 4);
      Ws[wk_ + 0][wn_] = w0.x; Ws[wk_ + 1][wn_] = w0.y;
      Ws[wk_ + 2][wn_] = w0.z; Ws[wk_ + 3][wn_] = w0.w;
      Ws[wk_ + 4][wn_] = w1.x; Ws[wk_ + 5][wn_] = w1.y;
      Ws[wk_ + 6][wn_] = w1.z; Ws[wk_ + 7][wn_] = w1.w;
    } else {
      float4 w0 = *(const float4*)(Wg + k0);
      Ws[wk_ + 0][wn_] = w0.x; Ws[wk_ + 1][wn_] = w0.y;
      Ws[wk_ + 2][wn_] = w0.z; Ws[wk_ + 3][wn_] = w0.w;
    }
    __syncthreads();
    #pragma unroll
    for (int kk = 0; kk < BK; ++kk) {
      float am[TM], wn[TN];
      *(float4*)&am[0] = *(const float4*)&As[kk][ty * TM];
      *(float4*)&am[4] = *(const float4*)&As[kk][ty * TM + 4];
      *(float4*)&wn[0] = *(const float4*)&Ws[kk][tx * TN];
      if (TN == 8) *(float4*)&wn[4] = *(const float4*)&Ws[kk][tx * TN + 4];
      #pragma unroll
      for (int i = 0; i < TM; ++i)
        #pragma unroll
        for (int j = 0; j < TN; ++j) acc[i][j] += am[i] * wn[j];
    }
    __syncthreads();
  }

  // epilogue
  #pragma unroll
  for (int i = 0; i < TM; ++i) {
    const int m = m0 + ty * TM + i;
    float* Cr = C + (size_t)m * N + n0 + tx * TN;
    const float* Rr = resid + (size_t)m * N + n0 + tx * TN;
    #pragma unroll
    for (int jc = 0; jc < TN; jc += 4) {
      float4 v;
      v.x = acc[i][jc + 0]; v.y = acc[i][jc + 1];
      v.z = acc[i][jc + 2]; v.w = acc[i][jc + 3];
      if (bias) {
        float4 bb = *(const float4*)(bias + n0 + tx * TN + jc);
        v.x += bb.x; v.y += bb.y; v.z += bb.z; v.w += bb.w;
      }
      if (GELU) {
        v.x = 0.5f * v.x * (1.0f + erff(v.x * 0.70710678118654752f));
        v.y = 0.5f * v.y * (1.0f + erff(v.y * 0.70710678118654752f));
        v.z = 0.5f * v.z * (1.0f + erff(v.z * 0.70710678118654752f));
        v.w = 0.5f * v.w * (1.0f + erff(v.w * 0.70710678118654752f));
      }
      if (RESID) {
        float4 rr = *(const float4*)(Rr + jc);
        v.x += rr.x; v.y += rr.y; v.z += rr.z; v.w += rr.w;
      }
      *(float4*)(Cr + jc) = v;
    }
  }
}

// ---------------------------------------------------------------------------
// RoPE + split + transpose: qkv (S,B,3,H,HD) -> qt/kt/vt (B,H,S,HD),
// rope applied to q,k.  One thread per (s,b,h,d).
// ---------------------------------------------------------------------------
__global__ __launch_bounds__(256) void rope_kernel(const float* __restrict__ qkv,
    const float* __restrict__ rot, float* __restrict__ qt,
    float* __restrict__ kt, float* __restrict__ vt) {
  const int idx = blockIdx.x * 256 + threadIdx.x;   // over S*B*H*HD = 2M
  const int d  = idx & 63;
  const int hh = (idx >> 6) & 15;
  const int m  = idx >> 10;        // s*B+b
  const int s  = m >> 1;
  const int b  = m & 1;
  const float f  = rot[s * 32 + (d & 31)];
  const float cs = cosf(f);
  const float sn = sinf(f);
  const float sign = (d < 32) ? -1.0f : 1.0f;
  const size_t base  = (size_t)m * 3072 + hh * 64;
  const size_t obase = (((size_t)(b * 16 + hh) * 1024 + s) << 6) + d;
  // q
  float qv = qkv[base + d];
  float qp = qkv[base + (d ^ 32)];
  qt[obase] = qv * cs + sign * qp * sn;
  // k
  float kv = qkv[base + 1024 + d];
  float kp = qkv[base + 1024 + (d ^ 32)];
  kt[obase] = kv * cs + sign * kp * sn;
  // v
  vt[obase] = qkv[base + 2048 + d];
}

// ---------------------------------------------------------------------------
// Flash attention, fp32, one wave per (b,h,query). lane = head dim.
// Online softmax; o written directly in (S,B,D) layout.
// ---------------------------------------------------------------------------
__global__ __launch_bounds__(256) void attn_kernel(const float* __restrict__ q,
    const float* __restrict__ k, const float* __restrict__ v,
    float* __restrict__ o) {
  const int wid  = (blockIdx.x * 256 + threadIdx.x) >> 6;  // 0..32767
  const int lane = threadIdx.x & 63;
  const int s  = wid & 1023;
  const int bh = wid >> 10;       // b*16+h
  const float* qp = q + (((size_t)bh * 1024 + s) << 6);
  const float* kb = k + ((size_t)bh << 16);
  const float* vb = v + ((size_t)bh << 16);
  const float qd = qp[lane];
  float mx = -3.0e38f, l = 0.f, acc = 0.f;
  for (int t = 0; t < 1024; ++t) {
    float p = qd * kb[t * 64 + lane];
    p += __shfl_xor(p, 32); p += __shfl_xor(p, 16); p += __shfl_xor(p, 8);
    p += __shfl_xor(p, 4);  p += __shfl_xor(p, 2);  p += __shfl_xor(p, 1);
    const float sc = p * 0.125f;              // 1/sqrt(64)
    const float mn = fmaxf(mx, sc);
    const float alpha = expf(mx - mn);
    const float w = expf(sc - mn);
    acc = acc * alpha + w * vb[t * 64 + lane];
    l   = l * alpha + w;
    mx  = mn;
  }
  const int b = bh >> 4, hh = bh & 15;
  o[(((size_t)s * 2 + b) << 10) + hh * 64 + lane] = acc / l;
}

// ---------------------------------------------------------------------------
// Mean over tokens: tsum[b,d] += sum_s h[s,b,d] (8 s-chunks, atomicAdd).
// ---------------------------------------------------------------------------
__global__ __launch_bounds__(256) void mean_kernel(const float* __restrict__ h,
    float* __restrict__ tsum) {
  const int idx = blockIdx.x * 256 + threadIdx.x;  // 64 blocks = 16384
  const int bd = idx & 2047;
  const int sc = idx >> 11;        // 0..7
  const int b = bd >> 10, d = bd & 1023;
  float sm = 0.f;
  for (int s = sc * 128; s < sc * 128 + 128; ++s)
    sm += h[(((size_t)s * 2 + b) << 10) + d];
  atomicAdd(&tsum[bd], sm);
}

// ---------------------------------------------------------------------------
// Small mat-vec: out[b,n] = sum_d in[b,d]*W[n,d] (+bias). Wave per output n.
// grid (N/4, B), block 256.
// ---------------------------------------------------------------------------
__global__ __launch_bounds__(256) void smallmv_kernel(const float* __restrict__ in,
    const float* __restrict__ W, const float* __restrict__ bias,
    float* __restrict__ out) {
  const int lane = threadIdx.x & 63;
  const int n = blockIdx.x * 4 + (threadIdx.x >> 6);
  const int b = blockIdx.y;
  const float* wr = W + (size_t)n * 1024;
  const float* xr = in + (size_t)b * 1024;
  float sm = 0.f;
  #pragma unroll
  for (int j = 0; j < 4; ++j) {
    float4 wv = *(const float4*)(wr + lane * 4 + j * 256);
    float4 xv = *(const float4*)(xr + lane * 4 + j * 256);
    sm += wv.x * xv.x + wv.y * xv.y + wv.z * xv.z + wv.w * xv.w;
  }
  #pragma unroll
  for (int off = 32; off; off >>= 1) sm += __shfl_xor(sm, off);
  if (lane == 0) out[(size_t)b * 1024 + n] = sm + (bias ? bias[n] : 0.f);
}

// ---------------------------------------------------------------------------
// Pooling cross-attention: 1 query per (b,h) = 32 waves. k/v rows are (s*B+b).
// ---------------------------------------------------------------------------
__global__ __launch_bounds__(256) void pool_attn_kernel(const float* __restrict__ q,
    const float* __restrict__ k, const float* __restrict__ v,
    float* __restrict__ o) {
  const int wid  = (blockIdx.x * 256 + threadIdx.x) >> 6;  // 0..31
  const int lane = threadIdx.x & 63;
  const int b = wid >> 4, hh = wid & 15;
  const float qd = q[(size_t)b * 1024 + hh * 64 + lane];
  float mx = -3.0e38f, l = 0.f, acc = 0.f;
  for (int t = 0; t < 1024; ++t) {
    const size_t ro = (((size_t)t * 2 + b) << 10) + hh * 64 + lane;
    float p = qd * k[ro];
    p += __shfl_xor(p, 32); p += __shfl_xor(p, 16); p += __shfl_xor(p, 8);
    p += __shfl_xor(p, 4);  p += __shfl_xor(p, 2);  p += __shfl_xor(p, 1);
    const float sc = p * 0.125f;
    const float mn = fmaxf(mx, sc);
    const float alpha = expf(mx - mn);
    const float w = expf(sc - mn);
    acc = acc * alpha + w * v[ro];
    l   = l * alpha + w;
    mx  = mn;
  }
  o[(size_t)b * 1024 + hh * 64 + lane] = acc / l;
}

// ---------------------------------------------------------------------------
extern "C" void kernel_launch(void* const* d_in, const int* in_sizes, int n_in,
                              void* d_out, int out_size, void* d_ws, size_t ws_size,
                              hipStream_t stream) {
  (void)in_sizes; (void)n_in; (void)out_size; (void)ws_size;
  const float* x     = (const float*)d_in[0];
  const float* rot   = (const float*)d_in[1];
  const float* ln1_w = (const float*)d_in[2];
  const float* ln1_b = (const float*)d_in[3];
  const float* in_w  = (const float*)d_in[4];
  const float* in_b  = (const float*)d_in[5];
  const float* out_w = (const float*)d_in[6];
  const float* out_b = (const float*)d_in[7];
  const float* ln2_w = (const float*)d_in[8];
  const float* ln2_b = (const float*)d_in[9];
  const float* fc_w  = (const float*)d_in[10];
  const float* fc_b  = (const float*)d_in[11];
  const float* cp_w  = (const float*)d_in[12];
  const float* cp_b  = (const float*)d_in[13];
  const float* pn_q_w = (const float*)d_in[14];
  const float* pn_q_b = (const float*)d_in[15];
  const float* pn_k_w = (const float*)d_in[16];
  const float* pn_k_b = (const float*)d_in[17];
  const float* pn_v_w = (const float*)d_in[18];
  const float* pn_v_b = (const float*)d_in[19];
  const float* pq_w  = (const float*)d_in[20];
  const float* pk_w  = (const float*)d_in[21];
  const float* pv_w  = (const float*)d_in[22];
  const float* pp_w  = (const float*)d_in[23];
  const float* pp_b  = (const float*)d_in[24];

  // workspace layout (floats). Total 20M floats = 80 MB.
  float* ws = (float*)d_ws;
  const size_t M1 = 1u << 20;
  float* h  = ws;              // 2M  (S,B,D) residual stream
  float* a  = ws + 2 * M1;     // 2M  LN output / xk
  float* r1 = ws + 4 * M1;     // 8M  qkv (6M) then mlp (8M) then xv (2M)
  float* qt = ws + 12 * M1;    // 2M  (B,H,S,HD)
  float* kt = ws + 14 * M1;    // 2M  / k_pool
  float* vt = ws + 16 * M1;    // 2M  / v_pool
  float* o  = ws + 18 * M1;    // 2M  attn out (S,B,D)
  // pooling scratch reuses qt (free after layers)
  float* tsum  = qt;           // 2048
  float* xq    = qt + 2048;    // 2048
  float* qpool = qt + 4096;    // 2048
  float* opool = qt + 6144;    // 2048

  hipMemcpyAsync(h, x, 2 * M1 * sizeof(float), hipMemcpyDeviceToDevice, stream);

  for (int l = 0; l < NLAYER; ++l) {
    ln_kernel<<<MROWS, 256, 0, stream>>>(h, ln1_w + l * DMODEL, ln1_b + l * DMODEL, a, 1.0f);
    gemm_bt<128, 8, false, false><<<dim3(3072 / 128, MROWS / 128), 256, 0, stream>>>(
        a, in_w + (size_t)l * 3072 * 1024, in_b + l * 3072, nullptr, r1,
        MROWS, 3072, 1024);
    rope_kernel<<<8192, 256, 0, stream>>>(r1, rot, qt, kt, vt);
    attn_kernel<<<8192, 256, 0, stream>>>(qt, kt, vt, o);
    gemm_bt<64, 4, false, true><<<dim3(1024 / 64, MROWS / 128), 256, 0, stream>>>(
        o, out_w + (size_t)l * 1024 * 1024, out_b + l * 1024, h, h,
        MROWS, 1024, 1024);
    ln_kernel<<<MROWS, 256, 0, stream>>>(h, ln2_w + l * DMODEL, ln2_b + l * DMODEL, a, 1.0f);
    gemm_bt<128, 8, true, false><<<dim3(4096 / 128, MROWS / 128), 256, 0, stream>>>(
        a, fc_w + (size_t)l * 4096 * 1024, fc_b + l * 4096, nullptr, r1,
        MROWS, 4096, 1024);
    gemm_bt<64, 4, false, true><<<dim3(1024 / 64, MROWS / 128), 256, 0, stream>>>(
        r1, cp_w + (size_t)l * 1024 * 4096, cp_b + l * 1024, h, h,
        MROWS, 1024, 4096);
  }

  // ---- attention pooling head ----
  hipMemsetAsync(tsum, 0, 2048 * sizeof(float), stream);
  mean_kernel<<<64, 256, 0, stream>>>(h, tsum);
  ln_kernel<<<BATCH, 256, 0, stream>>>(tsum, pn_q_w, pn_q_b, xq, 1.0f / S_LEN);
  ln_kernel<<<MROWS, 256, 0, stream>>>(h, pn_k_w, pn_k_b, a, 1.0f);   // xk
  ln_kernel<<<MROWS, 256, 0, stream>>>(h, pn_v_w, pn_v_b, r1, 1.0f);  // xv
  smallmv_kernel<<<dim3(256, BATCH), 256, 0, stream>>>(xq, pq_w, nullptr, qpool);
  gemm_bt<64, 4, false, false><<<dim3(1024 / 64, MROWS / 128), 256, 0, stream>>>(
      a, pk_w, nullptr, nullptr, kt, MROWS, 1024, 1024);   // k_pool
  gemm_bt<64, 4, false, false><<<dim3(1024 / 64, MROWS / 128), 256, 0, stream>>>(
      r1, pv_w, nullptr, nullptr, vt, MROWS, 1024, 1024);  // v_pool
  pool_attn_kernel<<<8, 256, 0, stream>>>(qpool, kt, vt, opool);
  smallmv_kernel<<<dim3(256, BATCH), 256, 0, stream>>>(opool, pp_w, pp_b, (float*)d_out);
}

// Round 2
// 9082.543 us; speedup vs baseline: 1.4312x; 1.4312x over previous
//
#include <hip/hip_runtime.h>
#include <math.h>

// Problem constants (from reference)
#define S_LEN  1024
#define BATCH  2
#define DMODEL 1024
#define NHEAD  16
#define HDIM   64
#define NLAYER 4
#define MLPD   4096
#define MROWS  (S_LEN*BATCH)   // 2048

// ---------------------------------------------------------------------------
// LayerNorm over last dim (D=1024). One block (256 thr) per row.
// ---------------------------------------------------------------------------
__global__ __launch_bounds__(256) void ln_kernel(const float* __restrict__ x,
    const float* __restrict__ w, const float* __restrict__ b,
    float* __restrict__ out, float inscale) {
  const int row = blockIdx.x;
  const int tid = threadIdx.x;
  const float* xr = x + (size_t)row * DMODEL;
  float4 v = *(const float4*)(xr + tid * 4);
  v.x *= inscale; v.y *= inscale; v.z *= inscale; v.w *= inscale;
  float s1 = v.x + v.y + v.z + v.w;
  float s2 = v.x*v.x + v.y*v.y + v.z*v.z + v.w*v.w;
  #pragma unroll
  for (int off = 32; off; off >>= 1) {
    s1 += __shfl_xor(s1, off);
    s2 += __shfl_xor(s2, off);
  }
  __shared__ float as1[4], as2[4];
  if ((tid & 63) == 0) { as1[tid >> 6] = s1; as2[tid >> 6] = s2; }
  __syncthreads();
  s1 = as1[0] + as1[1] + as1[2] + as1[3];
  s2 = as2[0] + as2[1] + as2[2] + as2[3];
  const float mean = s1 * (1.0f / DMODEL);
  const float var  = s2 * (1.0f / DMODEL) - mean * mean;
  const float r = rsqrtf(var + 1e-5f);
  float4 wv = *(const float4*)(w + tid * 4);
  float4 bv = *(const float4*)(b + tid * 4);
  float4 ov;
  ov.x = (v.x - mean) * r * wv.x + bv.x;
  ov.y = (v.y - mean) * r * wv.y + bv.y;
  ov.z = (v.z - mean) * r * wv.z + bv.z;
  ov.w = (v.w - mean) * r * wv.w + bv.w;
  *(float4*)(out + (size_t)row * DMODEL + tid * 4) = ov;
}

// ---------------------------------------------------------------------------
// C[M,N] = A[M,K] * W[N,K]^T (+bias[n]) (+resid) (opt GELU).  fp32.
// ---------------------------------------------------------------------------
template<int BN, int TN, bool GELU, bool RESID>
__global__ __launch_bounds__(256) void gemm_bt(
    const float* __restrict__ A, const float* __restrict__ W,
    const float* __restrict__ bias, const float* __restrict__ resid,
    float* __restrict__ C, int M, int N, int K) {
  constexpr int BM = 128, BK = 16, TM = 8;
  __shared__ float As[BK][BM];
  __shared__ float Ws[BK][BN];
  const int tid = threadIdx.x;
  const int tx = tid & 15;          // n group
  const int ty = tid >> 4;          // m group
  const int m0 = blockIdx.y * BM;
  const int n0 = blockIdx.x * BN;

  float acc[TM][TN];
  #pragma unroll
  for (int i = 0; i < TM; ++i)
    #pragma unroll
    for (int j = 0; j < TN; ++j) acc[i][j] = 0.f;

  const int lm = tid & 127;
  const int lk = (tid >> 7) * 8;
  const float* Ag = A + (size_t)(m0 + lm) * K + lk;
  int wn_, wk_;
  if (BN == 128) { wn_ = tid & 127; wk_ = (tid >> 7) * 8; }
  else           { wn_ = tid & 63;  wk_ = (tid >> 6) * 4; }
  const float* Wg = W + (size_t)(n0 + wn_) * K + wk_;

  for (int k0 = 0; k0 < K; k0 += BK) {
    float4 a0 = *(const float4*)(Ag + k0);
    float4 a1 = *(const float4*)(Ag + k0 + 4);
    As[lk + 0][lm] = a0.x; As[lk + 1][lm] = a0.y;
    As[lk + 2][lm] = a0.z; As[lk + 3][lm] = a0.w;
    As[lk + 4][lm] = a1.x; As[lk + 5][lm] = a1.y;
    As[lk + 6][lm] = a1.z; As[lk + 7][lm] = a1.w;
    if (BN == 128) {
      float4 w0 = *(const float4*)(Wg + k0);
      float4 w1 = *(const float4*)(Wg + k0 + 4);
      Ws[wk_ + 0][wn_] = w0.x; Ws[wk_ + 1][wn_] = w0.y;
      Ws[wk_ + 2][wn_] = w0.z; Ws[wk_ + 3][wn_] = w0.w;
      Ws[wk_ + 4][wn_] = w1.x; Ws[wk_ + 5][wn_] = w1.y;
      Ws[wk_ + 6][wn_] = w1.z; Ws[wk_ + 7][wn_] = w1.w;
    } else {
      float4 w0 = *(const float4*)(Wg + k0);
      Ws[wk_ + 0][wn_] = w0.x; Ws[wk_ + 1][wn_] = w0.y;
      Ws[wk_ + 2][wn_] = w0.z; Ws[wk_ + 3][wn_] = w0.w;
    }
    __syncthreads();
    #pragma unroll
    for (int kk = 0; kk < BK; ++kk) {
      float am[TM], wn[TN];
      *(float4*)&am[0] = *(const float4*)&As[kk][ty * TM];
      *(float4*)&am[4] = *(const float4*)&As[kk][ty * TM + 4];
      *(float4*)&wn[0] = *(const float4*)&Ws[kk][tx * TN];
      if (TN == 8) *(float4*)&wn[4] = *(const float4*)&Ws[kk][tx * TN + 4];
      #pragma unroll
      for (int i = 0; i < TM; ++i)
        #pragma unroll
        for (int j = 0; j < TN; ++j) acc[i][j] += am[i] * wn[j];
    }
    __syncthreads();
  }

  #pragma unroll
  for (int i = 0; i < TM; ++i) {
    const int m = m0 + ty * TM + i;
    float* Cr = C + (size_t)m * N + n0 + tx * TN;
    const float* Rr = resid + (size_t)m * N + n0 + tx * TN;
    #pragma unroll
    for (int jc = 0; jc < TN; jc += 4) {
      float4 v;
      v.x = acc[i][jc + 0]; v.y = acc[i][jc + 1];
      v.z = acc[i][jc + 2]; v.w = acc[i][jc + 3];
      if (bias) {
        float4 bb = *(const float4*)(bias + n0 + tx * TN + jc);
        v.x += bb.x; v.y += bb.y; v.z += bb.z; v.w += bb.w;
      }
      if (GELU) {
        v.x = 0.5f * v.x * (1.0f + erff(v.x * 0.70710678118654752f));
        v.y = 0.5f * v.y * (1.0f + erff(v.y * 0.70710678118654752f));
        v.z = 0.5f * v.z * (1.0f + erff(v.z * 0.70710678118654752f));
        v.w = 0.5f * v.w * (1.0f + erff(v.w * 0.70710678118654752f));
      }
      if (RESID) {
        float4 rr = *(const float4*)(Rr + jc);
        v.x += rr.x; v.y += rr.y; v.z += rr.z; v.w += rr.w;
      }
      *(float4*)(Cr + jc) = v;
    }
  }
}

// ---------------------------------------------------------------------------
// RoPE + split + transpose: qkv (S,B,3,H,HD) -> qt/kt/vt (B,H,S,HD).
// ---------------------------------------------------------------------------
__global__ __launch_bounds__(256) void rope_kernel(const float* __restrict__ qkv,
    const float* __restrict__ rot, float* __restrict__ qt,
    float* __restrict__ kt, float* __restrict__ vt) {
  const int idx = blockIdx.x * 256 + threadIdx.x;   // over S*B*H*HD = 2M
  const int d  = idx & 63;
  const int hh = (idx >> 6) & 15;
  const int m  = idx >> 10;        // s*B+b
  const int s  = m >> 1;
  const int b  = m & 1;
  const float f  = rot[s * 32 + (d & 31)];
  const float cs = cosf(f);
  const float sn = sinf(f);
  const float sign = (d < 32) ? -1.0f : 1.0f;
  const size_t base  = (size_t)m * 3072 + hh * 64;
  const size_t obase = (((size_t)(b * 16 + hh) * 1024 + s) << 6) + d;
  float qv = qkv[base + d];
  float qp = qkv[base + (d ^ 32)];
  qt[obase] = qv * cs + sign * qp * sn;
  float kv = qkv[base + 1024 + d];
  float kp = qkv[base + 1024 + (d ^ 32)];
  kt[obase] = kv * cs + sign * kp * sn;
  vt[obase] = qkv[base + 2048 + d];
}

// ---------------------------------------------------------------------------
// Flash attention v2: lane = query row. q-row and O-accumulator live in
// registers (64 VGPRs each); K/V staged to LDS coalesced, read back as
// lane-uniform broadcasts (conflict-free). Online softmax is per-lane scalar
// state: NO cross-lane ops in the hot loop.
// One wave per block; grid = B*H*(S/64) = 512.
// ---------------------------------------------------------------------------
__global__ __launch_bounds__(64, 1) void attn_kernel(const float* __restrict__ q,
    const float* __restrict__ k, const float* __restrict__ v,
    float* __restrict__ o) {
  const int lane  = threadIdx.x;
  const int blk   = blockIdx.x;      // 512
  const int qtile = blk & 15;
  const int bh    = blk >> 4;        // b*16+h
  const int sq    = qtile * 64 + lane;

  __shared__ float Ks[4096];
  __shared__ float Vs[4096];
  const float* kb = k + ((size_t)bh << 16);
  const float* vb = v + ((size_t)bh << 16);

  float qreg[64];
  {
    const float* qrow = q + (((size_t)bh * 1024 + sq) << 6);
    #pragma unroll
    for (int i = 0; i < 16; ++i)
      *(float4*)&qreg[i * 4] = *(const float4*)(qrow + i * 4);
  }
  float acc[64];
  #pragma unroll
  for (int i = 0; i < 64; ++i) acc[i] = 0.f;
  float m = -3.0e38f, l = 0.f;

  for (int t0 = 0; t0 < 1024; t0 += 64) {
    __syncthreads();
    // stage 64 keys + 64 values (rows are contiguous): coalesced float4
    #pragma unroll
    for (int i = 0; i < 16; ++i) {
      *(float4*)&Ks[i * 256 + lane * 4] =
          *(const float4*)(kb + (size_t)t0 * 64 + i * 256 + lane * 4);
      *(float4*)&Vs[i * 256 + lane * 4] =
          *(const float4*)(vb + (size_t)t0 * 64 + i * 256 + lane * 4);
    }
    __syncthreads();

    #pragma unroll
    for (int st = 0; st < 4; ++st) {
      float s[16];
      #pragma unroll
      for (int t = 0; t < 16; ++t) {
        const float* kr = &Ks[(st * 16 + t) * 64];
        float s0 = 0.f, s1 = 0.f, s2 = 0.f, s3 = 0.f;
        #pragma unroll
        for (int d = 0; d < 64; d += 16) {
          float4 k0 = *(const float4*)(kr + d);
          float4 k1 = *(const float4*)(kr + d + 4);
          float4 k2 = *(const float4*)(kr + d + 8);
          float4 k3 = *(const float4*)(kr + d + 12);
          s0 += k0.x*qreg[d]    + k0.y*qreg[d+1]  + k0.z*qreg[d+2]  + k0.w*qreg[d+3];
          s1 += k1.x*qreg[d+4]  + k1.y*qreg[d+5]  + k1.z*qreg[d+6]  + k1.w*qreg[d+7];
          s2 += k2.x*qreg[d+8]  + k2.y*qreg[d+9]  + k2.z*qreg[d+10] + k2.w*qreg[d+11];
          s3 += k3.x*qreg[d+12] + k3.y*qreg[d+13] + k3.z*qreg[d+14] + k3.w*qreg[d+15];
        }
        s[t] = (s0 + s1 + s2 + s3) * 0.125f;   // 1/sqrt(64)
      }
      float tm = s[0];
      #pragma unroll
      for (int t = 1; t < 16; ++t) tm = fmaxf(tm, s[t]);
      const float mn = fmaxf(m, tm);
      const float alpha = __expf(m - mn);
      m = mn;
      l *= alpha;
      #pragma unroll
      for (int i = 0; i < 64; ++i) acc[i] *= alpha;
      #pragma unroll
      for (int t = 0; t < 16; ++t) {
        const float w = __expf(s[t] - m);
        l += w;
        const float* vr = &Vs[(st * 16 + t) * 64];
        #pragma unroll
        for (int d = 0; d < 64; d += 4) {
          float4 vv = *(const float4*)(vr + d);
          acc[d]   += w * vv.x; acc[d+1] += w * vv.y;
          acc[d+2] += w * vv.z; acc[d+3] += w * vv.w;
        }
      }
    }
  }

  const int b = bh >> 4, hh = bh & 15;
  const float rl = 1.0f / l;
  float* orow = o + (((size_t)sq * 2 + b) << 10) + hh * 64;
  #pragma unroll
  for (int i = 0; i < 16; ++i) {
    float4 vv;
    vv.x = acc[i*4]   * rl; vv.y = acc[i*4+1] * rl;
    vv.z = acc[i*4+2] * rl; vv.w = acc[i*4+3] * rl;
    *(float4*)(orow + i * 4) = vv;
  }
}

// ---------------------------------------------------------------------------
// Mean over tokens: tsum[b,d] += sum_s h[s,b,d] (8 s-chunks, atomicAdd).
// ---------------------------------------------------------------------------
__global__ __launch_bounds__(256) void mean_kernel(const float* __restrict__ h,
    float* __restrict__ tsum) {
  const int idx = blockIdx.x * 256 + threadIdx.x;  // 64 blocks = 16384
  const int bd = idx & 2047;
  const int sc = idx >> 11;        // 0..7
  const int b = bd >> 10, d = bd & 1023;
  float sm = 0.f;
  for (int s = sc * 128; s < sc * 128 + 128; ++s)
    sm += h[(((size_t)s * 2 + b) << 10) + d];
  atomicAdd(&tsum[bd], sm);
}

// ---------------------------------------------------------------------------
// Small mat-vec: out[b,n] = sum_d in[b,d]*W[n,d] (+bias). Wave per output n.
// ---------------------------------------------------------------------------
__global__ __launch_bounds__(256) void smallmv_kernel(const float* __restrict__ in,
    const float* __restrict__ W, const float* __restrict__ bias,
    float* __restrict__ out) {
  const int lane = threadIdx.x & 63;
  const int n = blockIdx.x * 4 + (threadIdx.x >> 6);
  const int b = blockIdx.y;
  const float* wr = W + (size_t)n * 1024;
  const float* xr = in + (size_t)b * 1024;
  float sm = 0.f;
  #pragma unroll
  for (int j = 0; j < 4; ++j) {
    float4 wv = *(const float4*)(wr + lane * 4 + j * 256);
    float4 xv = *(const float4*)(xr + lane * 4 + j * 256);
    sm += wv.x * xv.x + wv.y * xv.y + wv.z * xv.z + wv.w * xv.w;
  }
  #pragma unroll
  for (int off = 32; off; off >>= 1) sm += __shfl_xor(sm, off);
  if (lane == 0) out[(size_t)b * 1024 + n] = sm + (bias ? bias[n] : 0.f);
}

// ---------------------------------------------------------------------------
// Pooling cross-attention: 1 query per (b,h) = 32 waves.
// ---------------------------------------------------------------------------
__global__ __launch_bounds__(256) void pool_attn_kernel(const float* __restrict__ q,
    const float* __restrict__ k, const float* __restrict__ v,
    float* __restrict__ o) {
  const int wid  = (blockIdx.x * 256 + threadIdx.x) >> 6;  // 0..31
  const int lane = threadIdx.x & 63;
  const int b = wid >> 4, hh = wid & 15;
  const float qd = q[(size_t)b * 1024 + hh * 64 + lane];
  float mx = -3.0e38f, l = 0.f, acc = 0.f;
  for (int t = 0; t < 1024; ++t) {
    const size_t ro = (((size_t)t * 2 + b) << 10) + hh * 64 + lane;
    float p = qd * k[ro];
    p += __shfl_xor(p, 32); p += __shfl_xor(p, 16); p += __shfl_xor(p, 8);
    p += __shfl_xor(p, 4);  p += __shfl_xor(p, 2);  p += __shfl_xor(p, 1);
    const float sc = p * 0.125f;
    const float mn = fmaxf(mx, sc);
    const float alpha = expf(mx - mn);
    const float w = expf(sc - mn);
    acc = acc * alpha + w * v[ro];
    l   = l * alpha + w;
    mx  = mn;
  }
  o[(size_t)b * 1024 + hh * 64 + lane] = acc / l;
}

// ---------------------------------------------------------------------------
extern "C" void kernel_launch(void* const* d_in, const int* in_sizes, int n_in,
                              void* d_out, int out_size, void* d_ws, size_t ws_size,
                              hipStream_t stream) {
  (void)in_sizes; (void)n_in; (void)out_size; (void)ws_size;
  const float* x     = (const float*)d_in[0];
  const float* rot   = (const float*)d_in[1];
  const float* ln1_w = (const float*)d_in[2];
  const float* ln1_b = (const float*)d_in[3];
  const float* in_w  = (const float*)d_in[4];
  const float* in_b  = (const float*)d_in[5];
  const float* out_w = (const float*)d_in[6];
  const float* out_b = (const float*)d_in[7];
  const float* ln2_w = (const float*)d_in[8];
  const float* ln2_b = (const float*)d_in[9];
  const float* fc_w  = (const float*)d_in[10];
  const float* fc_b  = (const float*)d_in[11];
  const float* cp_w  = (const float*)d_in[12];
  const float* cp_b  = (const float*)d_in[13];
  const float* pn_q_w = (const float*)d_in[14];
  const float* pn_q_b = (const float*)d_in[15];
  const float* pn_k_w = (const float*)d_in[16];
  const float* pn_k_b = (const float*)d_in[17];
  const float* pn_v_w = (const float*)d_in[18];
  const float* pn_v_b = (const float*)d_in[19];
  const float* pq_w  = (const float*)d_in[20];
  const float* pk_w  = (const float*)d_in[21];
  const float* pv_w  = (const float*)d_in[22];
  const float* pp_w  = (const float*)d_in[23];
  const float* pp_b  = (const float*)d_in[24];

  float* ws = (float*)d_ws;
  const size_t M1 = 1u << 20;
  float* h  = ws;              // 2M  (S,B,D) residual stream
  float* a  = ws + 2 * M1;     // 2M  LN output / xk
  float* r1 = ws + 4 * M1;     // 8M  qkv (6M) then mlp (8M) then xv (2M)
  float* qt = ws + 12 * M1;    // 2M  (B,H,S,HD)
  float* kt = ws + 14 * M1;    // 2M  / k_pool
  float* vt = ws + 16 * M1;    // 2M  / v_pool
  float* o  = ws + 18 * M1;    // 2M  attn out (S,B,D)
  float* tsum  = qt;           // pooling scratch reuses qt
  float* xq    = qt + 2048;
  float* qpool = qt + 4096;
  float* opool = qt + 6144;

  hipMemcpyAsync(h, x, 2 * M1 * sizeof(float), hipMemcpyDeviceToDevice, stream);

  for (int l = 0; l < NLAYER; ++l) {
    ln_kernel<<<MROWS, 256, 0, stream>>>(h, ln1_w + l * DMODEL, ln1_b + l * DMODEL, a, 1.0f);
    gemm_bt<128, 8, false, false><<<dim3(3072 / 128, MROWS / 128), 256, 0, stream>>>(
        a, in_w + (size_t)l * 3072 * 1024, in_b + l * 3072, nullptr, r1,
        MROWS, 3072, 1024);
    rope_kernel<<<8192, 256, 0, stream>>>(r1, rot, qt, kt, vt);
    attn_kernel<<<512, 64, 0, stream>>>(qt, kt, vt, o);
    gemm_bt<64, 4, false, true><<<dim3(1024 / 64, MROWS / 128), 256, 0, stream>>>(
        o, out_w + (size_t)l * 1024 * 1024, out_b + l * 1024, h, h,
        MROWS, 1024, 1024);
    ln_kernel<<<MROWS, 256, 0, stream>>>(h, ln2_w + l * DMODEL, ln2_b + l * DMODEL, a, 1.0f);
    gemm_bt<128, 8, true, false><<<dim3(4096 / 128, MROWS / 128), 256, 0, stream>>>(
        a, fc_w + (size_t)l * 4096 * 1024, fc_b + l * 4096, nullptr, r1,
        MROWS, 4096, 1024);
    gemm_bt<64, 4, false, true><<<dim3(1024 / 64, MROWS / 128), 256, 0, stream>>>(
        r1, cp_w + (size_t)l * 1024 * 4096, cp_b + l * 1024, h, h,
        MROWS, 1024, 4096);
  }

  // ---- attention pooling head ----
  hipMemsetAsync(tsum, 0, 2048 * sizeof(float), stream);
  mean_kernel<<<64, 256, 0, stream>>>(h, tsum);
  ln_kernel<<<BATCH, 256, 0, stream>>>(tsum, pn_q_w, pn_q_b, xq, 1.0f / S_LEN);
  ln_kernel<<<MROWS, 256, 0, stream>>>(h, pn_k_w, pn_k_b, a, 1.0f);   // xk
  ln_kernel<<<MROWS, 256, 0, stream>>>(h, pn_v_w, pn_v_b, r1, 1.0f);  // xv
  smallmv_kernel<<<dim3(256, BATCH), 256, 0, stream>>>(xq, pq_w, nullptr, qpool);
  gemm_bt<64, 4, false, false><<<dim3(1024 / 64, MROWS / 128), 256, 0, stream>>>(
      a, pk_w, nullptr, nullptr, kt, MROWS, 1024, 1024);   // k_pool
  gemm_bt<64, 4, false, false><<<dim3(1024 / 64, MROWS / 128), 256, 0, stream>>>(
      r1, pv_w, nullptr, nullptr, vt, MROWS, 1024, 1024);  // v_pool
  pool_attn_kernel<<<8, 256, 0, stream>>>(qpool, kt, vt, opool);
  smallmv_kernel<<<dim3(256, BATCH), 256, 0, stream>>>(opool, pp_w, pp_b, (float*)d_out);
}

// Round 3
// 2637.663 us; speedup vs baseline: 4.9281x; 3.4434x over previous
//
#include <hip/hip_runtime.h>
#include <math.h>

#define S_LEN  1024
#define BATCH  2
#define DMODEL 1024
#define NHEAD  16
#define HDIM   64
#define NLAYER 4
#define MLPD   4096
#define MROWS  (S_LEN*BATCH)   // 2048

typedef __attribute__((ext_vector_type(8))) short bf16x8_t;
typedef __attribute__((ext_vector_type(4))) float f32x4_t;

// fp32 -> bf16 round-to-nearest-even on the bit pattern
__device__ __forceinline__ unsigned short f2bf(float f) {
  union { float f; unsigned u; } c; c.f = f;
  return (unsigned short)((c.u + 0x7FFFu + ((c.u >> 16) & 1u)) >> 16);
}
__device__ __forceinline__ unsigned pk2(float lo, float hi) {
  return (unsigned)f2bf(lo) | ((unsigned)f2bf(hi) << 16);
}

// ---------------------------------------------------------------------------
// LayerNorm over last dim (D=1024). One block (256 thr) per row.
// BF16OUT: emit bf16 (feeds MFMA GEMM A operand).
// ---------------------------------------------------------------------------
template<bool BF16OUT>
__global__ __launch_bounds__(256) void ln_kernel(const float* __restrict__ x,
    const float* __restrict__ w, const float* __restrict__ b,
    void* __restrict__ out, float inscale) {
  const int row = blockIdx.x;
  const int tid = threadIdx.x;
  const float* xr = x + (size_t)row * DMODEL;
  float4 v = *(const float4*)(xr + tid * 4);
  v.x *= inscale; v.y *= inscale; v.z *= inscale; v.w *= inscale;
  float s1 = v.x + v.y + v.z + v.w;
  float s2 = v.x*v.x + v.y*v.y + v.z*v.z + v.w*v.w;
  #pragma unroll
  for (int off = 32; off; off >>= 1) {
    s1 += __shfl_xor(s1, off);
    s2 += __shfl_xor(s2, off);
  }
  __shared__ float as1[4], as2[4];
  if ((tid & 63) == 0) { as1[tid >> 6] = s1; as2[tid >> 6] = s2; }
  __syncthreads();
  s1 = as1[0] + as1[1] + as1[2] + as1[3];
  s2 = as2[0] + as2[1] + as2[2] + as2[3];
  const float mean = s1 * (1.0f / DMODEL);
  const float var  = s2 * (1.0f / DMODEL) - mean * mean;
  const float r = rsqrtf(var + 1e-5f);
  float4 wv = *(const float4*)(w + tid * 4);
  float4 bv = *(const float4*)(b + tid * 4);
  float o0 = (v.x - mean) * r * wv.x + bv.x;
  float o1 = (v.y - mean) * r * wv.y + bv.y;
  float o2 = (v.z - mean) * r * wv.z + bv.z;
  float o3 = (v.w - mean) * r * wv.w + bv.w;
  if (BF16OUT) {
    ushort4 u; u.x = f2bf(o0); u.y = f2bf(o1); u.z = f2bf(o2); u.w = f2bf(o3);
    *(ushort4*)((unsigned short*)out + (size_t)row * DMODEL + tid * 4) = u;
  } else {
    float4 ov; ov.x = o0; ov.y = o1; ov.z = o2; ov.w = o3;
    *(float4*)((float*)out + (size_t)row * DMODEL + tid * 4) = ov;
  }
}

// ---------------------------------------------------------------------------
// MFMA GEMM: C[M,N] = A_bf16[M,K] * W_f32[N,K]^T (+bias) (opt GELU/RESID).
// W converted fp32->bf16 (RNE) inline during staging. BK=32.
// BM=128: 4 waves 2x2, each 64x64 (4x4 16x16 frags).  grid (N/128, M/128)
// BM= 64: 4 waves 1x4, each 64x32 (4x2 frags).        grid (N/128, M/64)
// LDS row stride 40 bf16 (80B): frag ds_read_b128 at <=2-way bank aliasing.
// ---------------------------------------------------------------------------
template<int BM, bool GELU, bool RESID, bool OUTBF16>
__global__ __launch_bounds__(256) void gemm_mfma(
    const unsigned short* __restrict__ A, const float* __restrict__ W,
    const float* __restrict__ bias, const float* __restrict__ resid,
    void* __restrict__ Cout, int M, int N, int K) {
  constexpr int BK = 32;
  constexpr int LDA = 40;              // bf16 elements per LDS row
  constexpr int NI = 4;
  constexpr int NJ = (BM == 128) ? 4 : 2;
  __shared__ __align__(16) unsigned short As[BM * LDA];
  __shared__ __align__(16) unsigned short Bs[128 * LDA];
  const int tid  = threadIdx.x;
  const int wid  = tid >> 6;
  const int lane = tid & 63;
  const int lrow = lane & 15;
  const int lq   = lane >> 4;
  const int m0 = blockIdx.y * BM;
  const int n0 = blockIdx.x * 128;
  const int wm = (BM == 128) ? (wid >> 1) * 64 : 0;
  const int wn = (BM == 128) ? (wid & 1) * 64  : wid * 32;

  f32x4_t acc[NI][NJ];
  #pragma unroll
  for (int i = 0; i < NI; ++i)
    #pragma unroll
    for (int j = 0; j < NJ; ++j) acc[i][j] = (f32x4_t){0.f, 0.f, 0.f, 0.f};

  int ar, ak;
  if (BM == 128) { ar = tid >> 1; ak = (tid & 1) * 16; }
  else           { ar = tid >> 2; ak = (tid & 3) * 8; }
  const unsigned short* Ag = A + (size_t)(m0 + ar) * K + ak;
  const int wr = tid >> 1, wk = (tid & 1) * 16;
  const float* Wg = W + (size_t)(n0 + wr) * K + wk;

  for (int k0 = 0; k0 < K; k0 += BK) {
    uint4 a0, a1;
    a0 = *(const uint4*)(Ag + k0);
    if (BM == 128) a1 = *(const uint4*)(Ag + k0 + 8);
    float4 w0 = *(const float4*)(Wg + k0);
    float4 w1 = *(const float4*)(Wg + k0 + 4);
    float4 w2 = *(const float4*)(Wg + k0 + 8);
    float4 w3 = *(const float4*)(Wg + k0 + 12);
    uint4 q0, q1;
    q0.x = pk2(w0.x, w0.y); q0.y = pk2(w0.z, w0.w);
    q0.z = pk2(w1.x, w1.y); q0.w = pk2(w1.z, w1.w);
    q1.x = pk2(w2.x, w2.y); q1.y = pk2(w2.z, w2.w);
    q1.z = pk2(w3.x, w3.y); q1.w = pk2(w3.z, w3.w);

    __syncthreads();   // previous iteration's frag reads complete
    *(uint4*)&As[ar * LDA + ak] = a0;
    if (BM == 128) *(uint4*)&As[ar * LDA + ak + 8] = a1;
    *(uint4*)&Bs[wr * LDA + wk] = q0;
    *(uint4*)&Bs[wr * LDA + wk + 8] = q1;
    __syncthreads();   // staging visible

    bf16x8_t af[NI], bfr[NJ];
    #pragma unroll
    for (int i = 0; i < NI; ++i)
      af[i] = *(const bf16x8_t*)&As[(wm + i * 16 + lrow) * LDA + lq * 8];
    #pragma unroll
    for (int j = 0; j < NJ; ++j)
      bfr[j] = *(const bf16x8_t*)&Bs[(wn + j * 16 + lrow) * LDA + lq * 8];
    #pragma unroll
    for (int i = 0; i < NI; ++i)
      #pragma unroll
      for (int j = 0; j < NJ; ++j)
        acc[i][j] = __builtin_amdgcn_mfma_f32_16x16x32_bf16(af[i], bfr[j], acc[i][j], 0, 0, 0);
  }

  // epilogue: C/D layout col=lane&15, row=(lane>>4)*4+r  [m89/m91 verified]
  float bj[NJ];
  #pragma unroll
  for (int j = 0; j < NJ; ++j)
    bj[j] = bias ? bias[n0 + wn + j * 16 + lrow] : 0.f;
  #pragma unroll
  for (int i = 0; i < NI; ++i) {
    #pragma unroll
    for (int r = 0; r < 4; ++r) {
      const int row = m0 + wm + i * 16 + lq * 4 + r;
      const size_t idx = (size_t)row * N + n0 + wn + lrow;
      #pragma unroll
      for (int j = 0; j < NJ; ++j) {
        float val = acc[i][j][r] + bj[j];
        if (GELU)
          val = 0.5f * val * (1.0f + erff(val * 0.70710678118654752f));
        if (RESID)
          val += resid[idx + j * 16];
        if (OUTBF16)
          ((unsigned short*)Cout)[idx + j * 16] = f2bf(val);
        else
          ((float*)Cout)[idx + j * 16] = val;
      }
    }
  }
}

// ---------------------------------------------------------------------------
// RoPE + split + transpose: qkv (S,B,3,H,HD) fp32 -> qt/kt/vt (B,H,S,HD) fp32.
// ---------------------------------------------------------------------------
__global__ __launch_bounds__(256) void rope_kernel(const float* __restrict__ qkv,
    const float* __restrict__ rot, float* __restrict__ qt,
    float* __restrict__ kt, float* __restrict__ vt) {
  const int idx = blockIdx.x * 256 + threadIdx.x;   // over S*B*H*HD = 2M
  const int d  = idx & 63;
  const int hh = (idx >> 6) & 15;
  const int m  = idx >> 10;        // s*B+b
  const int s  = m >> 1;
  const int b  = m & 1;
  const float f  = rot[s * 32 + (d & 31)];
  const float cs = cosf(f);
  const float sn = sinf(f);
  const float sign = (d < 32) ? -1.0f : 1.0f;
  const size_t base  = (size_t)m * 3072 + hh * 64;
  const size_t obase = (((size_t)(b * 16 + hh) * 1024 + s) << 6) + d;
  float qv = qkv[base + d];
  float qp = qkv[base + (d ^ 32)];
  qt[obase] = qv * cs + sign * qp * sn;
  float kv = qkv[base + 1024 + d];
  float kp = qkv[base + 1024 + (d ^ 32)];
  kt[obase] = kv * cs + sign * kp * sn;
  vt[obase] = qkv[base + 2048 + d];
}

// ---------------------------------------------------------------------------
// Flash attention v3: split-K x4 + lane-pair per query.
// Block = 4 waves = (bh, 32-query tile); wave w owns keys [256w, 256w+256).
// lane = q*2+hf: lane pair shares a query, each half owns 32 of 64 dims
// (qreg/acc = 32 VGPRs each). Per-wave private LDS staging (16-key tiles,
// row stride 68 floats = 16B-aligned, conflict-light). Online softmax is
// per-lane scalar; one __shfl_xor(.,1) per key to join dot halves.
// Merge: (m,l) exchange via small LDS; scaled partials through regions.
// Output written as bf16 (feeds out-proj MFMA A).
// ---------------------------------------------------------------------------
__global__ __launch_bounds__(256, 4) void attn_kernel(const float* __restrict__ q,
    const float* __restrict__ k, const float* __restrict__ v,
    unsigned short* __restrict__ o) {
  const int tid  = threadIdx.x;
  const int wid  = tid >> 6;
  const int lane = tid & 63;
  const int qv   = lane >> 1;      // query in tile
  const int hf   = lane & 1;       // d-half
  const int blk   = blockIdx.x;    // 1024
  const int qtile = blk & 31;
  const int bh    = blk >> 5;
  const int sq    = qtile * 32 + qv;

  __shared__ __align__(16) float reg_[4 * 2176];
  __shared__ float ml[4][2][32];
  float* reg  = reg_ + wid * 2176;   // K: [16][68]
  float* Vreg = reg + 16 * 68;       // V: [16][68]

  const float* kb = k + ((size_t)bh << 16) + (size_t)wid * 256 * 64;
  const float* vb = v + ((size_t)bh << 16) + (size_t)wid * 256 * 64;

  float qreg[32];
  {
    const float* qrow = q + (((size_t)bh * 1024 + sq) << 6) + hf * 32;
    #pragma unroll
    for (int i = 0; i < 8; ++i)
      *(float4*)&qreg[i * 4] = *(const float4*)(qrow + i * 4);
  }
  float acc[32];
  #pragma unroll
  for (int i = 0; i < 32; ++i) acc[i] = 0.f;
  float m = -3.0e38f, l = 0.f;

  const int skey = lane >> 2;       // staging: key row
  const int sdc  = (lane & 3) * 16; // staging: d-chunk

  for (int t0 = 0; t0 < 256; t0 += 16) {
    __syncthreads();
    {
      const float* gk = kb + (size_t)(t0 + skey) * 64 + sdc;
      const float* gv = vb + (size_t)(t0 + skey) * 64 + sdc;
      float4 k0 = *(const float4*)(gk);
      float4 k1 = *(const float4*)(gk + 4);
      float4 k2 = *(const float4*)(gk + 8);
      float4 k3 = *(const float4*)(gk + 12);
      float4 v0 = *(const float4*)(gv);
      float4 v1 = *(const float4*)(gv + 4);
      float4 v2 = *(const float4*)(gv + 8);
      float4 v3 = *(const float4*)(gv + 12);
      float* wk = reg  + skey * 68 + sdc;
      float* wv = Vreg + skey * 68 + sdc;
      *(float4*)(wk)      = k0; *(float4*)(wk + 4)  = k1;
      *(float4*)(wk + 8)  = k2; *(float4*)(wk + 12) = k3;
      *(float4*)(wv)      = v0; *(float4*)(wv + 4)  = v1;
      *(float4*)(wv + 8)  = v2; *(float4*)(wv + 12) = v3;
    }
    __syncthreads();

    float s[16];
    #pragma unroll
    for (int t = 0; t < 16; ++t) {
      const float* kr = reg + t * 68 + hf * 32;
      float s0 = 0.f, s1 = 0.f, s2 = 0.f, s3 = 0.f;
      #pragma unroll
      for (int d = 0; d < 32; d += 16) {
        float4 k0 = *(const float4*)(kr + d);
        float4 k1 = *(const float4*)(kr + d + 4);
        float4 k2 = *(const float4*)(kr + d + 8);
        float4 k3 = *(const float4*)(kr + d + 12);
        s0 += k0.x*qreg[d]    + k0.y*qreg[d+1]  + k0.z*qreg[d+2]  + k0.w*qreg[d+3];
        s1 += k1.x*qreg[d+4]  + k1.y*qreg[d+5]  + k1.z*qreg[d+6]  + k1.w*qreg[d+7];
        s2 += k2.x*qreg[d+8]  + k2.y*qreg[d+9]  + k2.z*qreg[d+10] + k2.w*qreg[d+11];
        s3 += k3.x*qreg[d+12] + k3.y*qreg[d+13] + k3.z*qreg[d+14] + k3.w*qreg[d+15];
      }
      float half = s0 + s1 + s2 + s3;
      s[t] = (half + __shfl_xor(half, 1)) * 0.125f;   // join halves, 1/sqrt(64)
    }
    float tm = s[0];
    #pragma unroll
    for (int t = 1; t < 16; ++t) tm = fmaxf(tm, s[t]);
    const float mn = fmaxf(m, tm);
    const float alpha = __expf(m - mn);
    m = mn;
    l *= alpha;
    #pragma unroll
    for (int d = 0; d < 32; ++d) acc[d] *= alpha;
    #pragma unroll
    for (int t = 0; t < 16; ++t) {
      const float w8 = __expf(s[t] - m);
      l += w8;
      const float* vr = Vreg + t * 68 + hf * 32;
      #pragma unroll
      for (int d = 0; d < 32; d += 4) {
        float4 vv = *(const float4*)(vr + d);
        acc[d]   += w8 * vv.x; acc[d+1] += w8 * vv.y;
        acc[d+2] += w8 * vv.z; acc[d+3] += w8 * vv.w;
      }
    }
  }

  __syncthreads();
  ml[wid][0][qv] = m;     // both halves write same value
  ml[wid][1][qv] = l;
  __syncthreads();
  const float M = fmaxf(fmaxf(ml[0][0][qv], ml[1][0][qv]),
                        fmaxf(ml[2][0][qv], ml[3][0][qv]));
  const float f = __expf(m - M);
  {
    float* orow = reg + qv * 68 + hf * 32;   // overwrite own staging region
    #pragma unroll
    for (int d = 0; d < 32; d += 4) {
      float4 vv;
      vv.x = acc[d] * f;   vv.y = acc[d+1] * f;
      vv.z = acc[d+2] * f; vv.w = acc[d+3] * f;
      *(float4*)(orow + d) = vv;
    }
  }
  __syncthreads();

  // final combine: thread t -> (q = t>>3, d-chunk = (t&7)*8)
  const int fq = tid >> 3, fc = (tid & 7) * 8;
  float M2 = fmaxf(fmaxf(ml[0][0][fq], ml[1][0][fq]),
                   fmaxf(ml[2][0][fq], ml[3][0][fq]));
  float L = 0.f;
  #pragma unroll
  for (int w = 0; w < 4; ++w)
    L += __expf(ml[w][0][fq] - M2) * ml[w][1][fq];
  const float inv = 1.0f / L;
  float ov[8];
  #pragma unroll
  for (int j = 0; j < 8; ++j) ov[j] = 0.f;
  #pragma unroll
  for (int w = 0; w < 4; ++w) {
    const float* rr = reg_ + w * 2176 + fq * 68 + fc;
    float4 r0 = *(const float4*)(rr);
    float4 r1 = *(const float4*)(rr + 4);
    ov[0] += r0.x; ov[1] += r0.y; ov[2] += r0.z; ov[3] += r0.w;
    ov[4] += r1.x; ov[5] += r1.y; ov[6] += r1.z; ov[7] += r1.w;
  }
  const int b = bh >> 4, hh = bh & 15;
  const int sq2 = qtile * 32 + fq;
  unsigned short* orow = o + (((size_t)sq2 * 2 + b) << 10) + hh * 64 + fc;
  ushort4 u0, u1;
  u0.x = f2bf(ov[0] * inv); u0.y = f2bf(ov[1] * inv);
  u0.z = f2bf(ov[2] * inv); u0.w = f2bf(ov[3] * inv);
  u1.x = f2bf(ov[4] * inv); u1.y = f2bf(ov[5] * inv);
  u1.z = f2bf(ov[6] * inv); u1.w = f2bf(ov[7] * inv);
  *(ushort4*)(orow)     = u0;
  *(ushort4*)(orow + 4) = u1;
}

// ---------------------------------------------------------------------------
// Mean over tokens: tsum[b,d] += sum_s h[s,b,d] (8 s-chunks, atomicAdd).
// ---------------------------------------------------------------------------
__global__ __launch_bounds__(256) void mean_kernel(const float* __restrict__ h,
    float* __restrict__ tsum) {
  const int idx = blockIdx.x * 256 + threadIdx.x;  // 64 blocks = 16384
  const int bd = idx & 2047;
  const int sc = idx >> 11;
  const int b = bd >> 10, d = bd & 1023;
  float sm = 0.f;
  for (int s = sc * 128; s < sc * 128 + 128; ++s)
    sm += h[(((size_t)s * 2 + b) << 10) + d];
  atomicAdd(&tsum[bd], sm);
}

// ---------------------------------------------------------------------------
// Small mat-vec: out[b,n] = sum_d in[b,d]*W[n,d] (+bias). Wave per output n.
// ---------------------------------------------------------------------------
__global__ __launch_bounds__(256) void smallmv_kernel(const float* __restrict__ in,
    const float* __restrict__ W, const float* __restrict__ bias,
    float* __restrict__ out) {
  const int lane = threadIdx.x & 63;
  const int n = blockIdx.x * 4 + (threadIdx.x >> 6);
  const int b = blockIdx.y;
  const float* wr = W + (size_t)n * 1024;
  const float* xr = in + (size_t)b * 1024;
  float sm = 0.f;
  #pragma unroll
  for (int j = 0; j < 4; ++j) {
    float4 wv = *(const float4*)(wr + lane * 4 + j * 256);
    float4 xv = *(const float4*)(xr + lane * 4 + j * 256);
    sm += wv.x * xv.x + wv.y * xv.y + wv.z * xv.z + wv.w * xv.w;
  }
  #pragma unroll
  for (int off = 32; off; off >>= 1) sm += __shfl_xor(sm, off);
  if (lane == 0) out[(size_t)b * 1024 + n] = sm + (bias ? bias[n] : 0.f);
}

// ---------------------------------------------------------------------------
// Pooling cross-attention: 1 query per (b,h) = 32 waves.
// ---------------------------------------------------------------------------
__global__ __launch_bounds__(256) void pool_attn_kernel(const float* __restrict__ q,
    const float* __restrict__ k, const float* __restrict__ v,
    float* __restrict__ o) {
  const int wid  = (blockIdx.x * 256 + threadIdx.x) >> 6;  // 0..31
  const int lane = threadIdx.x & 63;
  const int b = wid >> 4, hh = wid & 15;
  const float qd = q[(size_t)b * 1024 + hh * 64 + lane];
  float mx = -3.0e38f, l = 0.f, acc = 0.f;
  for (int t = 0; t < 1024; ++t) {
    const size_t ro = (((size_t)t * 2 + b) << 10) + hh * 64 + lane;
    float p = qd * k[ro];
    p += __shfl_xor(p, 32); p += __shfl_xor(p, 16); p += __shfl_xor(p, 8);
    p += __shfl_xor(p, 4);  p += __shfl_xor(p, 2);  p += __shfl_xor(p, 1);
    const float sc = p * 0.125f;
    const float mn = fmaxf(mx, sc);
    const float alpha = expf(mx - mn);
    const float w = expf(sc - mn);
    acc = acc * alpha + w * v[ro];
    l   = l * alpha + w;
    mx  = mn;
  }
  o[(size_t)b * 1024 + hh * 64 + lane] = acc / l;
}

// ---------------------------------------------------------------------------
extern "C" void kernel_launch(void* const* d_in, const int* in_sizes, int n_in,
                              void* d_out, int out_size, void* d_ws, size_t ws_size,
                              hipStream_t stream) {
  (void)in_sizes; (void)n_in; (void)out_size; (void)ws_size;
  const float* x     = (const float*)d_in[0];
  const float* rot   = (const float*)d_in[1];
  const float* ln1_w = (const float*)d_in[2];
  const float* ln1_b = (const float*)d_in[3];
  const float* in_w  = (const float*)d_in[4];
  const float* in_b  = (const float*)d_in[5];
  const float* out_w = (const float*)d_in[6];
  const float* out_b = (const float*)d_in[7];
  const float* ln2_w = (const float*)d_in[8];
  const float* ln2_b = (const float*)d_in[9];
  const float* fc_w  = (const float*)d_in[10];
  const float* fc_b  = (const float*)d_in[11];
  const float* cp_w  = (const float*)d_in[12];
  const float* cp_b  = (const float*)d_in[13];
  const float* pn_q_w = (const float*)d_in[14];
  const float* pn_q_b = (const float*)d_in[15];
  const float* pn_k_w = (const float*)d_in[16];
  const float* pn_k_b = (const float*)d_in[17];
  const float* pn_v_w = (const float*)d_in[18];
  const float* pn_v_b = (const float*)d_in[19];
  const float* pq_w  = (const float*)d_in[20];
  const float* pk_w  = (const float*)d_in[21];
  const float* pv_w  = (const float*)d_in[22];
  const float* pp_w  = (const float*)d_in[23];
  const float* pp_b  = (const float*)d_in[24];

  float* ws = (float*)d_ws;
  const size_t M1 = 1u << 20;
  float* h  = ws;              // 2M fl  (S,B,D) residual stream, fp32
  float* a  = ws + 2 * M1;     // 2M fl  LN out (bf16 in-place) / xk bf16
  float* r1 = ws + 4 * M1;     // 8M fl  qkv fp32 (6M) / mlp bf16 / xv bf16
  float* qt = ws + 12 * M1;    // 2M fl  (B,H,S,HD) fp32
  float* kt = ws + 14 * M1;    // 2M fl  / k_pool fp32
  float* vt = ws + 16 * M1;    // 2M fl  / v_pool fp32
  float* o  = ws + 18 * M1;    // attn out (S,B,D) bf16 (2M elems in 2M fl)
  unsigned short* a_bf  = (unsigned short*)a;
  unsigned short* r1_bf = (unsigned short*)r1;
  unsigned short* o_bf  = (unsigned short*)o;
  float* tsum  = qt;           // pooling scratch reuses qt
  float* xq    = qt + 2048;
  float* qpool = qt + 4096;
  float* opool = qt + 6144;

  hipMemcpyAsync(h, x, 2 * M1 * sizeof(float), hipMemcpyDeviceToDevice, stream);

  for (int l = 0; l < NLAYER; ++l) {
    ln_kernel<true><<<MROWS, 256, 0, stream>>>(h, ln1_w + l * DMODEL, ln1_b + l * DMODEL, a_bf, 1.0f);
    // QKV: (2048,3072,1024) -> r1 fp32
    gemm_mfma<128, false, false, false><<<dim3(3072 / 128, MROWS / 128), 256, 0, stream>>>(
        a_bf, in_w + (size_t)l * 3072 * 1024, in_b + l * 3072, nullptr, r1,
        MROWS, 3072, 1024);
    rope_kernel<<<8192, 256, 0, stream>>>(r1, rot, qt, kt, vt);
    attn_kernel<<<1024, 256, 0, stream>>>(qt, kt, vt, o_bf);
    // out-proj: (2048,1024,1024) + resid -> h fp32
    gemm_mfma<64, false, true, false><<<dim3(1024 / 128, MROWS / 64), 256, 0, stream>>>(
        o_bf, out_w + (size_t)l * 1024 * 1024, out_b + l * 1024, h, h,
        MROWS, 1024, 1024);
    ln_kernel<true><<<MROWS, 256, 0, stream>>>(h, ln2_w + l * DMODEL, ln2_b + l * DMODEL, a_bf, 1.0f);
    // FC + GELU: (2048,4096,1024) -> r1 bf16
    gemm_mfma<128, true, false, true><<<dim3(4096 / 128, MROWS / 128), 256, 0, stream>>>(
        a_bf, fc_w + (size_t)l * 4096 * 1024, fc_b + l * 4096, nullptr, r1_bf,
        MROWS, 4096, 1024);
    // c_proj: (2048,1024,4096) + resid -> h fp32
    gemm_mfma<64, false, true, false><<<dim3(1024 / 128, MROWS / 64), 256, 0, stream>>>(
        r1_bf, cp_w + (size_t)l * 1024 * 4096, cp_b + l * 1024, h, h,
        MROWS, 1024, 4096);
  }

  // ---- attention pooling head ----
  hipMemsetAsync(tsum, 0, 2048 * sizeof(float), stream);
  mean_kernel<<<64, 256, 0, stream>>>(h, tsum);
  ln_kernel<false><<<BATCH, 256, 0, stream>>>(tsum, pn_q_w, pn_q_b, xq, 1.0f / S_LEN);
  ln_kernel<true><<<MROWS, 256, 0, stream>>>(h, pn_k_w, pn_k_b, a_bf, 1.0f);    // xk bf16
  ln_kernel<true><<<MROWS, 256, 0, stream>>>(h, pn_v_w, pn_v_b, r1_bf, 1.0f);   // xv bf16
  smallmv_kernel<<<dim3(256, BATCH), 256, 0, stream>>>(xq, pq_w, nullptr, qpool);
  gemm_mfma<64, false, false, false><<<dim3(1024 / 128, MROWS / 64), 256, 0, stream>>>(
      a_bf, pk_w, nullptr, nullptr, kt, MROWS, 1024, 1024);   // k_pool fp32
  gemm_mfma<64, false, false, false><<<dim3(1024 / 128, MROWS / 64), 256, 0, stream>>>(
      r1_bf, pv_w, nullptr, nullptr, vt, MROWS, 1024, 1024);  // v_pool fp32
  pool_attn_kernel<<<8, 256, 0, stream>>>(qpool, kt, vt, opool);
  smallmv_kernel<<<dim3(256, BATCH), 256, 0, stream>>>(opool, pp_w, pp_b, (float*)d_out);
}

// Round 4
// 1712.392 us; speedup vs baseline: 7.5909x; 1.5403x over previous
//
#include <hip/hip_runtime.h>
#include <math.h>

#define S_LEN  1024
#define BATCH  2
#define DMODEL 1024
#define NHEAD  16
#define HDIM   64
#define NLAYER 4
#define MLPD   4096
#define MROWS  (S_LEN*BATCH)   // 2048

typedef __attribute__((ext_vector_type(8))) short bf16x8_t;
typedef __attribute__((ext_vector_type(4))) float f32x4_t;

// fp32 -> bf16 round-to-nearest-even on the bit pattern
__device__ __forceinline__ unsigned short f2bf(float f) {
  union { float f; unsigned u; } c; c.f = f;
  return (unsigned short)((c.u + 0x7FFFu + ((c.u >> 16) & 1u)) >> 16);
}
__device__ __forceinline__ unsigned pk2(float lo, float hi) {
  return (unsigned)f2bf(lo) | ((unsigned)f2bf(hi) << 16);
}

// ---------------------------------------------------------------------------
// LayerNorm over last dim (D=1024). One block (256 thr) per row.
// ---------------------------------------------------------------------------
template<bool BF16OUT>
__global__ __launch_bounds__(256) void ln_kernel(const float* __restrict__ x,
    const float* __restrict__ w, const float* __restrict__ b,
    void* __restrict__ out, float inscale) {
  const int row = blockIdx.x;
  const int tid = threadIdx.x;
  const float* xr = x + (size_t)row * DMODEL;
  float4 v = *(const float4*)(xr + tid * 4);
  v.x *= inscale; v.y *= inscale; v.z *= inscale; v.w *= inscale;
  float s1 = v.x + v.y + v.z + v.w;
  float s2 = v.x*v.x + v.y*v.y + v.z*v.z + v.w*v.w;
  #pragma unroll
  for (int off = 32; off; off >>= 1) {
    s1 += __shfl_xor(s1, off);
    s2 += __shfl_xor(s2, off);
  }
  __shared__ float as1[4], as2[4];
  if ((tid & 63) == 0) { as1[tid >> 6] = s1; as2[tid >> 6] = s2; }
  __syncthreads();
  s1 = as1[0] + as1[1] + as1[2] + as1[3];
  s2 = as2[0] + as2[1] + as2[2] + as2[3];
  const float mean = s1 * (1.0f / DMODEL);
  const float var  = s2 * (1.0f / DMODEL) - mean * mean;
  const float r = rsqrtf(var + 1e-5f);
  float4 wv = *(const float4*)(w + tid * 4);
  float4 bv = *(const float4*)(b + tid * 4);
  float o0 = (v.x - mean) * r * wv.x + bv.x;
  float o1 = (v.y - mean) * r * wv.y + bv.y;
  float o2 = (v.z - mean) * r * wv.z + bv.z;
  float o3 = (v.w - mean) * r * wv.w + bv.w;
  if (BF16OUT) {
    ushort4 u; u.x = f2bf(o0); u.y = f2bf(o1); u.z = f2bf(o2); u.w = f2bf(o3);
    *(ushort4*)((unsigned short*)out + (size_t)row * DMODEL + tid * 4) = u;
  } else {
    float4 ov; ov.x = o0; ov.y = o1; ov.z = o2; ov.w = o3;
    *(float4*)((float*)out + (size_t)row * DMODEL + tid * 4) = ov;
  }
}

// ---------------------------------------------------------------------------
// MFMA GEMM: C[M,N] = A_bf16[M,K] * W_f32[N,K]^T (+bias) (opt GELU/RESID).
// W converted fp32->bf16 (RNE) inline during staging. BK=32.
// ---------------------------------------------------------------------------
template<int BM, bool GELU, bool RESID, bool OUTBF16>
__global__ __launch_bounds__(256) void gemm_mfma(
    const unsigned short* __restrict__ A, const float* __restrict__ W,
    const float* __restrict__ bias, const float* __restrict__ resid,
    void* __restrict__ Cout, int M, int N, int K) {
  constexpr int BK = 32;
  constexpr int LDA = 40;
  constexpr int NI = 4;
  constexpr int NJ = (BM == 128) ? 4 : 2;
  __shared__ __align__(16) unsigned short As[BM * LDA];
  __shared__ __align__(16) unsigned short Bs[128 * LDA];
  const int tid  = threadIdx.x;
  const int wid  = tid >> 6;
  const int lane = tid & 63;
  const int lrow = lane & 15;
  const int lq   = lane >> 4;
  const int m0 = blockIdx.y * BM;
  const int n0 = blockIdx.x * 128;
  const int wm = (BM == 128) ? (wid >> 1) * 64 : 0;
  const int wn = (BM == 128) ? (wid & 1) * 64  : wid * 32;

  f32x4_t acc[NI][NJ];
  #pragma unroll
  for (int i = 0; i < NI; ++i)
    #pragma unroll
    for (int j = 0; j < NJ; ++j) acc[i][j] = (f32x4_t){0.f, 0.f, 0.f, 0.f};

  int ar, ak;
  if (BM == 128) { ar = tid >> 1; ak = (tid & 1) * 16; }
  else           { ar = tid >> 2; ak = (tid & 3) * 8; }
  const unsigned short* Ag = A + (size_t)(m0 + ar) * K + ak;
  const int wr = tid >> 1, wk = (tid & 1) * 16;
  const float* Wg = W + (size_t)(n0 + wr) * K + wk;

  for (int k0 = 0; k0 < K; k0 += BK) {
    uint4 a0, a1;
    a0 = *(const uint4*)(Ag + k0);
    if (BM == 128) a1 = *(const uint4*)(Ag + k0 + 8);
    float4 w0 = *(const float4*)(Wg + k0);
    float4 w1 = *(const float4*)(Wg + k0 + 4);
    float4 w2 = *(const float4*)(Wg + k0 + 8);
    float4 w3 = *(const float4*)(Wg + k0 + 12);
    uint4 q0, q1;
    q0.x = pk2(w0.x, w0.y); q0.y = pk2(w0.z, w0.w);
    q0.z = pk2(w1.x, w1.y); q0.w = pk2(w1.z, w1.w);
    q1.x = pk2(w2.x, w2.y); q1.y = pk2(w2.z, w2.w);
    q1.z = pk2(w3.x, w3.y); q1.w = pk2(w3.z, w3.w);

    __syncthreads();
    *(uint4*)&As[ar * LDA + ak] = a0;
    if (BM == 128) *(uint4*)&As[ar * LDA + ak + 8] = a1;
    *(uint4*)&Bs[wr * LDA + wk] = q0;
    *(uint4*)&Bs[wr * LDA + wk + 8] = q1;
    __syncthreads();

    bf16x8_t af[NI], bfr[NJ];
    #pragma unroll
    for (int i = 0; i < NI; ++i)
      af[i] = *(const bf16x8_t*)&As[(wm + i * 16 + lrow) * LDA + lq * 8];
    #pragma unroll
    for (int j = 0; j < NJ; ++j)
      bfr[j] = *(const bf16x8_t*)&Bs[(wn + j * 16 + lrow) * LDA + lq * 8];
    #pragma unroll
    for (int i = 0; i < NI; ++i)
      #pragma unroll
      for (int j = 0; j < NJ; ++j)
        acc[i][j] = __builtin_amdgcn_mfma_f32_16x16x32_bf16(af[i], bfr[j], acc[i][j], 0, 0, 0);
  }

  float bj[NJ];
  #pragma unroll
  for (int j = 0; j < NJ; ++j)
    bj[j] = bias ? bias[n0 + wn + j * 16 + lrow] : 0.f;
  #pragma unroll
  for (int i = 0; i < NI; ++i) {
    #pragma unroll
    for (int r = 0; r < 4; ++r) {
      const int row = m0 + wm + i * 16 + lq * 4 + r;
      const size_t idx = (size_t)row * N + n0 + wn + lrow;
      #pragma unroll
      for (int j = 0; j < NJ; ++j) {
        float val = acc[i][j][r] + bj[j];
        if (GELU)
          val = 0.5f * val * (1.0f + erff(val * 0.70710678118654752f));
        if (RESID)
          val += resid[idx + j * 16];
        if (OUTBF16)
          ((unsigned short*)Cout)[idx + j * 16] = f2bf(val);
        else
          ((float*)Cout)[idx + j * 16] = val;
      }
    }
  }
}

// ---------------------------------------------------------------------------
// RoPE + split + transpose, bf16 out:
//   qt,kt: (B,H,S,64);  vt: (B,H,64,S)  (transposed for PV MFMA B-operand).
// ---------------------------------------------------------------------------
__global__ __launch_bounds__(256) void rope_kernel(const float* __restrict__ qkv,
    const float* __restrict__ rot, unsigned short* __restrict__ qt,
    unsigned short* __restrict__ kt, unsigned short* __restrict__ vt) {
  const int idx = blockIdx.x * 256 + threadIdx.x;   // over S*B*H*HD = 2M
  const int d  = idx & 63;
  const int hh = (idx >> 6) & 15;
  const int m  = idx >> 10;        // s*B+b
  const int s  = m >> 1;
  const int b  = m & 1;
  const float f  = rot[s * 32 + (d & 31)];
  const float cs = cosf(f);
  const float sn = sinf(f);
  const float sign = (d < 32) ? -1.0f : 1.0f;
  const size_t base  = (size_t)m * 3072 + hh * 64;
  const int bh = b * 16 + hh;
  const size_t obase = (((size_t)bh * 1024 + s) << 6) + d;
  float qv = qkv[base + d];
  float qp = qkv[base + (d ^ 32)];
  qt[obase] = f2bf(qv * cs + sign * qp * sn);
  float kv = qkv[base + 1024 + d];
  float kp = qkv[base + 1024 + (d ^ 32)];
  kt[obase] = f2bf(kv * cs + sign * kp * sn);
  vt[(((size_t)bh * 64 + d) << 10) + s] = f2bf(qkv[base + 2048 + d]);
}

// ---------------------------------------------------------------------------
// MFMA flash attention. Block = 4 waves, 64 queries (16 per wave), one bh.
// Q A-frags resident in regs. Loop over 64-key tiles: stage K (keys x 72)
// and V^T (dims x 72) in LDS; QK^T via 16x16x32 MFMA; row softmax on C
// layout (col=lane&15=key, row=quad*4+r=query) with shfl_xor over the
// 16-lane col group; P -> per-wave LDS (bf16) -> A-frags; PV via MFMA.
// Output bf16 (S,B,D).
// ---------------------------------------------------------------------------
__global__ __launch_bounds__(256, 2) void attn_kernel(
    const unsigned short* __restrict__ q, const unsigned short* __restrict__ k,
    const unsigned short* __restrict__ vtr, unsigned short* __restrict__ o) {
  const int tid  = threadIdx.x;
  const int wid  = tid >> 6;
  const int lane = tid & 63;
  const int col  = lane & 15;
  const int quad = lane >> 4;
  const int bh   = blockIdx.x >> 4;
  const int qw   = (blockIdx.x & 15) * 64 + wid * 16;  // wave's query base

  __shared__ __align__(16) unsigned short Ks[64 * 72];
  __shared__ __align__(16) unsigned short Vs[64 * 72];
  __shared__ __align__(16) unsigned short Pl_[4][16 * 72];
  unsigned short* Pl = Pl_[wid];

  const unsigned short* kb = k   + ((size_t)bh << 16);
  const unsigned short* vb = vtr + ((size_t)bh << 16);

  // Q fragments: A[m=col][kd=quad*8+j (+32)]
  bf16x8_t qa0, qa1;
  {
    const unsigned short* qp = q + ((((size_t)bh << 10) + qw + col) << 6) + quad * 8;
    qa0 = *(const bf16x8_t*)(qp);
    qa1 = *(const bf16x8_t*)(qp + 32);
  }

  f32x4_t oacc[4];
  #pragma unroll
  for (int j = 0; j < 4; ++j) oacc[j] = (f32x4_t){0.f, 0.f, 0.f, 0.f};
  float mr[4] = {-3.0e38f, -3.0e38f, -3.0e38f, -3.0e38f};
  float lr[4] = {0.f, 0.f, 0.f, 0.f};

  const int srow = tid >> 2;          // staging row 0..63
  const int scol = (tid & 3) * 16;    // elem offset

  for (int t0 = 0; t0 < 1024; t0 += 64) {
    __syncthreads();
    {
      const unsigned short* gk = kb + (size_t)(t0 + srow) * 64 + scol;
      const unsigned short* gv = vb + (size_t)srow * 1024 + t0 + scol;
      uint4 ka = *(const uint4*)(gk);
      uint4 kc = *(const uint4*)(gk + 8);
      uint4 va = *(const uint4*)(gv);
      uint4 vc = *(const uint4*)(gv + 8);
      *(uint4*)&Ks[srow * 72 + scol]     = ka;
      *(uint4*)&Ks[srow * 72 + scol + 8] = kc;
      *(uint4*)&Vs[srow * 72 + scol]     = va;
      *(uint4*)&Vs[srow * 72 + scol + 8] = vc;
    }
    __syncthreads();

    // ---- QK^T: 4 n-tiles of 16 keys, K=64 via 2 MFMA each ----
    f32x4_t sc[4];
    #pragma unroll
    for (int j = 0; j < 4; ++j) {
      bf16x8_t kf0 = *(const bf16x8_t*)&Ks[(j * 16 + col) * 72 + quad * 8];
      bf16x8_t kf1 = *(const bf16x8_t*)&Ks[(j * 16 + col) * 72 + quad * 8 + 32];
      f32x4_t c = (f32x4_t){0.f, 0.f, 0.f, 0.f};
      c = __builtin_amdgcn_mfma_f32_16x16x32_bf16(qa0, kf0, c, 0, 0, 0);
      c = __builtin_amdgcn_mfma_f32_16x16x32_bf16(qa1, kf1, c, 0, 0, 0);
      sc[j] = c;
    }

    // ---- online softmax per query row (r), cols distributed over 16 lanes
    #pragma unroll
    for (int r = 0; r < 4; ++r) {
      float s0 = sc[0][r] * 0.125f, s1 = sc[1][r] * 0.125f;
      float s2 = sc[2][r] * 0.125f, s3 = sc[3][r] * 0.125f;
      float rm = fmaxf(fmaxf(s0, s1), fmaxf(s2, s3));
      rm = fmaxf(rm, __shfl_xor(rm, 1));
      rm = fmaxf(rm, __shfl_xor(rm, 2));
      rm = fmaxf(rm, __shfl_xor(rm, 4));
      rm = fmaxf(rm, __shfl_xor(rm, 8));
      const float mn = fmaxf(mr[r], rm);
      const float alpha = __expf(mr[r] - mn);
      mr[r] = mn;
      const float p0 = __expf(s0 - mn), p1 = __expf(s1 - mn);
      const float p2 = __expf(s2 - mn), p3 = __expf(s3 - mn);
      float rs = p0 + p1 + p2 + p3;
      rs += __shfl_xor(rs, 1);
      rs += __shfl_xor(rs, 2);
      rs += __shfl_xor(rs, 4);
      rs += __shfl_xor(rs, 8);
      lr[r] = lr[r] * alpha + rs;
      #pragma unroll
      for (int j = 0; j < 4; ++j) oacc[j][r] *= alpha;
      const int prow = (quad * 4 + r) * 72;
      Pl[prow +  0 + col] = f2bf(p0);
      Pl[prow + 16 + col] = f2bf(p1);
      Pl[prow + 32 + col] = f2bf(p2);
      Pl[prow + 48 + col] = f2bf(p3);
    }

    // ---- PV: A = P[q=col][k=key], B = V^T[n=dim][k=key] ----
    bf16x8_t pa0 = *(const bf16x8_t*)&Pl[col * 72 + quad * 8];
    bf16x8_t pa1 = *(const bf16x8_t*)&Pl[col * 72 + quad * 8 + 32];
    #pragma unroll
    for (int j = 0; j < 4; ++j) {
      bf16x8_t vf0 = *(const bf16x8_t*)&Vs[(j * 16 + col) * 72 + quad * 8];
      bf16x8_t vf1 = *(const bf16x8_t*)&Vs[(j * 16 + col) * 72 + quad * 8 + 32];
      oacc[j] = __builtin_amdgcn_mfma_f32_16x16x32_bf16(pa0, vf0, oacc[j], 0, 0, 0);
      oacc[j] = __builtin_amdgcn_mfma_f32_16x16x32_bf16(pa1, vf1, oacc[j], 0, 0, 0);
    }
  }

  // epilogue: O row = qw + quad*4 + r, dim = j*16 + col
  const int b = bh >> 4, hh = bh & 15;
  #pragma unroll
  for (int r = 0; r < 4; ++r) {
    const float inv = 1.0f / lr[r];
    const int sq = qw + quad * 4 + r;
    unsigned short* orow = o + (((size_t)sq * 2 + b) << 10) + hh * 64;
    #pragma unroll
    for (int j = 0; j < 4; ++j)
      orow[j * 16 + col] = f2bf(oacc[j][r] * inv);
  }
}

// ---------------------------------------------------------------------------
// Mean over tokens: tsum[b,d] += sum_s h[s,b,d] (8 s-chunks, atomicAdd).
// ---------------------------------------------------------------------------
__global__ __launch_bounds__(256) void mean_kernel(const float* __restrict__ h,
    float* __restrict__ tsum) {
  const int idx = blockIdx.x * 256 + threadIdx.x;
  const int bd = idx & 2047;
  const int sc = idx >> 11;
  const int b = bd >> 10, d = bd & 1023;
  float sm = 0.f;
  for (int s = sc * 128; s < sc * 128 + 128; ++s)
    sm += h[(((size_t)s * 2 + b) << 10) + d];
  atomicAdd(&tsum[bd], sm);
}

// ---------------------------------------------------------------------------
// Small mat-vec: out[b,n] = sum_d in[b,d]*W[n,d] (+bias). Wave per output n.
// ---------------------------------------------------------------------------
__global__ __launch_bounds__(256) void smallmv_kernel(const float* __restrict__ in,
    const float* __restrict__ W, const float* __restrict__ bias,
    float* __restrict__ out) {
  const int lane = threadIdx.x & 63;
  const int n = blockIdx.x * 4 + (threadIdx.x >> 6);
  const int b = blockIdx.y;
  const float* wr = W + (size_t)n * 1024;
  const float* xr = in + (size_t)b * 1024;
  float sm = 0.f;
  #pragma unroll
  for (int j = 0; j < 4; ++j) {
    float4 wv = *(const float4*)(wr + lane * 4 + j * 256);
    float4 xv = *(const float4*)(xr + lane * 4 + j * 256);
    sm += wv.x * xv.x + wv.y * xv.y + wv.z * xv.z + wv.w * xv.w;
  }
  #pragma unroll
  for (int off = 32; off; off >>= 1) sm += __shfl_xor(sm, off);
  if (lane == 0) out[(size_t)b * 1024 + n] = sm + (bias ? bias[n] : 0.f);
}

// ---------------------------------------------------------------------------
// Pooling cross-attention, split-K: 512 waves, each (bh, 64-key block).
// Partials (m, l, acc[64]) at part[wid*68] {m,l,_,_,acc...}.
// ---------------------------------------------------------------------------
__global__ __launch_bounds__(256) void pool_attn_part(const float* __restrict__ q,
    const float* __restrict__ k, const float* __restrict__ v,
    float* __restrict__ part) {
  const int wid  = (blockIdx.x * 256 + threadIdx.x) >> 6;  // 0..511
  const int lane = threadIdx.x & 63;
  const int bh = wid >> 4, kblk = wid & 15;
  const int b = bh >> 4, hh = bh & 15;
  const float qd = q[(size_t)b * 1024 + hh * 64 + lane];
  float mx = -3.0e38f, l = 0.f, acc = 0.f;
  for (int t = kblk * 64; t < kblk * 64 + 64; ++t) {
    const size_t ro = (((size_t)t * 2 + b) << 10) + hh * 64 + lane;
    float p = qd * k[ro];
    p += __shfl_xor(p, 32); p += __shfl_xor(p, 16); p += __shfl_xor(p, 8);
    p += __shfl_xor(p, 4);  p += __shfl_xor(p, 2);  p += __shfl_xor(p, 1);
    const float sc = p * 0.125f;
    const float mn = fmaxf(mx, sc);
    const float alpha = __expf(mx - mn);
    const float w = __expf(sc - mn);
    acc = acc * alpha + w * v[ro];
    l   = l * alpha + w;
    mx  = mn;
  }
  float* pp = part + (size_t)wid * 68;
  if (lane == 0) { pp[0] = mx; pp[1] = l; }
  pp[4 + lane] = acc;
}

__global__ __launch_bounds__(256) void pool_attn_comb(const float* __restrict__ part,
    float* __restrict__ o) {
  const int wid  = (blockIdx.x * 256 + threadIdx.x) >> 6;  // 0..31 = bh
  const int lane = threadIdx.x & 63;
  const float* pb = part + (size_t)wid * 16 * 68;
  float M = -3.0e38f;
  #pragma unroll
  for (int w = 0; w < 16; ++w) M = fmaxf(M, pb[w * 68]);
  float L = 0.f, O = 0.f;
  #pragma unroll
  for (int w = 0; w < 16; ++w) {
    const float e = __expf(pb[w * 68] - M);
    L += e * pb[w * 68 + 1];
    O += e * pb[w * 68 + 4 + lane];
  }
  const int b = wid >> 4, hh = wid & 15;
  o[(size_t)b * 1024 + hh * 64 + lane] = O / L;
}

// ---------------------------------------------------------------------------
extern "C" void kernel_launch(void* const* d_in, const int* in_sizes, int n_in,
                              void* d_out, int out_size, void* d_ws, size_t ws_size,
                              hipStream_t stream) {
  (void)in_sizes; (void)n_in; (void)out_size; (void)ws_size;
  const float* x     = (const float*)d_in[0];
  const float* rot   = (const float*)d_in[1];
  const float* ln1_w = (const float*)d_in[2];
  const float* ln1_b = (const float*)d_in[3];
  const float* in_w  = (const float*)d_in[4];
  const float* in_b  = (const float*)d_in[5];
  const float* out_w = (const float*)d_in[6];
  const float* out_b = (const float*)d_in[7];
  const float* ln2_w = (const float*)d_in[8];
  const float* ln2_b = (const float*)d_in[9];
  const float* fc_w  = (const float*)d_in[10];
  const float* fc_b  = (const float*)d_in[11];
  const float* cp_w  = (const float*)d_in[12];
  const float* cp_b  = (const float*)d_in[13];
  const float* pn_q_w = (const float*)d_in[14];
  const float* pn_q_b = (const float*)d_in[15];
  const float* pn_k_w = (const float*)d_in[16];
  const float* pn_k_b = (const float*)d_in[17];
  const float* pn_v_w = (const float*)d_in[18];
  const float* pn_v_b = (const float*)d_in[19];
  const float* pq_w  = (const float*)d_in[20];
  const float* pk_w  = (const float*)d_in[21];
  const float* pv_w  = (const float*)d_in[22];
  const float* pp_w  = (const float*)d_in[23];
  const float* pp_b  = (const float*)d_in[24];

  float* ws = (float*)d_ws;
  const size_t M1 = 1u << 20;
  float* h  = ws;              // 2M fl  (S,B,D) residual stream fp32
  float* a  = ws + 2 * M1;     // LN out bf16 / xk bf16
  float* r1 = ws + 4 * M1;     // qkv fp32 (6M) / mlp bf16 / xv bf16
  float* qt = ws + 12 * M1;    // q bf16 (B,H,S,64)  | pooling scratch
  float* kt = ws + 14 * M1;    // k bf16 (B,H,S,64)  | k_pool fp32
  float* vt = ws + 16 * M1;    // v^T bf16 (B,H,64,S)| v_pool fp32
  float* o  = ws + 18 * M1;    // attn out bf16 (S,B,D)
  unsigned short* a_bf  = (unsigned short*)a;
  unsigned short* r1_bf = (unsigned short*)r1;
  unsigned short* o_bf  = (unsigned short*)o;
  unsigned short* qt_bf = (unsigned short*)qt;
  unsigned short* kt_bf = (unsigned short*)kt;
  unsigned short* vt_bf = (unsigned short*)vt;
  float* tsum  = qt;           // pooling scratch reuses qt region
  float* xq    = qt + 2048;
  float* qpool = qt + 4096;
  float* opool = qt + 6144;
  float* ppart = qt + 8192;    // 512*68 floats

  hipMemcpyAsync(h, x, 2 * M1 * sizeof(float), hipMemcpyDeviceToDevice, stream);

  for (int l = 0; l < NLAYER; ++l) {
    ln_kernel<true><<<MROWS, 256, 0, stream>>>(h, ln1_w + l * DMODEL, ln1_b + l * DMODEL, a_bf, 1.0f);
    gemm_mfma<128, false, false, false><<<dim3(3072 / 128, MROWS / 128), 256, 0, stream>>>(
        a_bf, in_w + (size_t)l * 3072 * 1024, in_b + l * 3072, nullptr, r1,
        MROWS, 3072, 1024);
    rope_kernel<<<8192, 256, 0, stream>>>(r1, rot, qt_bf, kt_bf, vt_bf);
    attn_kernel<<<512, 256, 0, stream>>>(qt_bf, kt_bf, vt_bf, o_bf);
    gemm_mfma<64, false, true, false><<<dim3(1024 / 128, MROWS / 64), 256, 0, stream>>>(
        o_bf, out_w + (size_t)l * 1024 * 1024, out_b + l * 1024, h, h,
        MROWS, 1024, 1024);
    ln_kernel<true><<<MROWS, 256, 0, stream>>>(h, ln2_w + l * DMODEL, ln2_b + l * DMODEL, a_bf, 1.0f);
    gemm_mfma<128, true, false, true><<<dim3(4096 / 128, MROWS / 128), 256, 0, stream>>>(
        a_bf, fc_w + (size_t)l * 4096 * 1024, fc_b + l * 4096, nullptr, r1_bf,
        MROWS, 4096, 1024);
    gemm_mfma<64, false, true, false><<<dim3(1024 / 128, MROWS / 64), 256, 0, stream>>>(
        r1_bf, cp_w + (size_t)l * 1024 * 4096, cp_b + l * 1024, h, h,
        MROWS, 1024, 4096);
  }

  // ---- attention pooling head ----
  hipMemsetAsync(tsum, 0, 2048 * sizeof(float), stream);
  mean_kernel<<<64, 256, 0, stream>>>(h, tsum);
  ln_kernel<false><<<BATCH, 256, 0, stream>>>(tsum, pn_q_w, pn_q_b, xq, 1.0f / S_LEN);
  ln_kernel<true><<<MROWS, 256, 0, stream>>>(h, pn_k_w, pn_k_b, a_bf, 1.0f);    // xk bf16
  ln_kernel<true><<<MROWS, 256, 0, stream>>>(h, pn_v_w, pn_v_b, r1_bf, 1.0f);   // xv bf16
  smallmv_kernel<<<dim3(256, BATCH), 256, 0, stream>>>(xq, pq_w, nullptr, qpool);
  gemm_mfma<64, false, false, false><<<dim3(1024 / 128, MROWS / 64), 256, 0, stream>>>(
      a_bf, pk_w, nullptr, nullptr, kt, MROWS, 1024, 1024);   // k_pool fp32
  gemm_mfma<64, false, false, false><<<dim3(1024 / 128, MROWS / 64), 256, 0, stream>>>(
      r1_bf, pv_w, nullptr, nullptr, vt, MROWS, 1024, 1024);  // v_pool fp32
  pool_attn_part<<<128, 256, 0, stream>>>(qpool, kt, vt, ppart);
  pool_attn_comb<<<8, 256, 0, stream>>>(ppart, opool);
  smallmv_kernel<<<dim3(256, BATCH), 256, 0, stream>>>(opool, pp_w, pp_b, (float*)d_out);
}

// Round 5
// 1348.067 us; speedup vs baseline: 9.6424x; 1.2703x over previous
//
#include <hip/hip_runtime.h>
#include <math.h>

#define S_LEN  1024
#define BATCH  2
#define DMODEL 1024
#define NHEAD  16
#define HDIM   64
#define NLAYER 4
#define MLPD   4096
#define MROWS  (S_LEN*BATCH)   // 2048

typedef __attribute__((ext_vector_type(8))) short bf16x8_t;
typedef __attribute__((ext_vector_type(4))) float f32x4_t;

// fp32 -> bf16 round-to-nearest-even on the bit pattern
__device__ __forceinline__ unsigned short f2bf(float f) {
  union { float f; unsigned u; } c; c.f = f;
  return (unsigned short)((c.u + 0x7FFFu + ((c.u >> 16) & 1u)) >> 16);
}
__device__ __forceinline__ unsigned pk2(float lo, float hi) {
  return (unsigned)f2bf(lo) | ((unsigned)f2bf(hi) << 16);
}

// ---------------------------------------------------------------------------
// LayerNorm over last dim (D=1024). One block (256 thr) per row.
// ---------------------------------------------------------------------------
template<bool BF16OUT>
__global__ __launch_bounds__(256) void ln_kernel(const float* __restrict__ x,
    const float* __restrict__ w, const float* __restrict__ b,
    void* __restrict__ out, float inscale) {
  const int row = blockIdx.x;
  const int tid = threadIdx.x;
  const float* xr = x + (size_t)row * DMODEL;
  float4 v = *(const float4*)(xr + tid * 4);
  v.x *= inscale; v.y *= inscale; v.z *= inscale; v.w *= inscale;
  float s1 = v.x + v.y + v.z + v.w;
  float s2 = v.x*v.x + v.y*v.y + v.z*v.z + v.w*v.w;
  #pragma unroll
  for (int off = 32; off; off >>= 1) {
    s1 += __shfl_xor(s1, off);
    s2 += __shfl_xor(s2, off);
  }
  __shared__ float as1[4], as2[4];
  if ((tid & 63) == 0) { as1[tid >> 6] = s1; as2[tid >> 6] = s2; }
  __syncthreads();
  s1 = as1[0] + as1[1] + as1[2] + as1[3];
  s2 = as2[0] + as2[1] + as2[2] + as2[3];
  const float mean = s1 * (1.0f / DMODEL);
  const float var  = s2 * (1.0f / DMODEL) - mean * mean;
  const float r = rsqrtf(var + 1e-5f);
  float4 wv = *(const float4*)(w + tid * 4);
  float4 bv = *(const float4*)(b + tid * 4);
  float o0 = (v.x - mean) * r * wv.x + bv.x;
  float o1 = (v.y - mean) * r * wv.y + bv.y;
  float o2 = (v.z - mean) * r * wv.z + bv.z;
  float o3 = (v.w - mean) * r * wv.w + bv.w;
  if (BF16OUT) {
    ushort4 u; u.x = f2bf(o0); u.y = f2bf(o1); u.z = f2bf(o2); u.w = f2bf(o3);
    *(ushort4*)((unsigned short*)out + (size_t)row * DMODEL + tid * 4) = u;
  } else {
    float4 ov; ov.x = o0; ov.y = o1; ov.z = o2; ov.w = o3;
    *(float4*)((float*)out + (size_t)row * DMODEL + tid * 4) = ov;
  }
}

// ---------------------------------------------------------------------------
// MFMA GEMM v2: C[M,N] (+)= A_bf16[M,K] * W_f32[N,K]^T (+bias) (opt GELU).
// 128x128 tile, BK=32, 4 waves 2x2 (each 64x64 = 4x4 16x16x32 frags).
// SPLIT-K via grid.z (atomicAdd fp32 into Cout; bias added by z==0 only).
// Register-prefetch pipeline: next tile's global loads issue right after the
// staging barrier, overlapping ds_read+MFMA of the current tile.
// ---------------------------------------------------------------------------
template<int SPLIT, bool GELU, bool ATOMIC, bool OUTBF16>
__global__ __launch_bounds__(256, 2) void gemm_mfma(
    const unsigned short* __restrict__ A, const float* __restrict__ W,
    const float* __restrict__ bias, void* __restrict__ Cout,
    int M, int N, int K) {
  constexpr int BK = 32;
  constexpr int LDA = 40;              // bf16 elems per LDS row (80 B)
  __shared__ __align__(16) unsigned short As[128 * LDA];
  __shared__ __align__(16) unsigned short Bs[128 * LDA];
  const int tid  = threadIdx.x;
  const int wid  = tid >> 6;
  const int lane = tid & 63;
  const int lrow = lane & 15;
  const int lq   = lane >> 4;
  const int m0 = blockIdx.y * 128;
  const int n0 = blockIdx.x * 128;
  const int wm = (wid >> 1) * 64;
  const int wn = (wid & 1) * 64;
  const int Kc = K / SPLIT;
  const int kbase = blockIdx.z * Kc;

  f32x4_t acc[4][4];
  #pragma unroll
  for (int i = 0; i < 4; ++i)
    #pragma unroll
    for (int j = 0; j < 4; ++j) acc[i][j] = (f32x4_t){0.f, 0.f, 0.f, 0.f};

  const int ar = tid >> 1;             // row 0..127 (A row / W row)
  const int ak = (tid & 1) * 16;       // 16 elems per thread
  const unsigned short* Ag = A + (size_t)(m0 + ar) * K + kbase + ak;
  const float* Wg = W + (size_t)(n0 + ar) * K + kbase + ak;

  // prologue: prefetch tile 0
  uint4 a_pf0 = *(const uint4*)(Ag);
  uint4 a_pf1 = *(const uint4*)(Ag + 8);
  float4 w_pf0 = *(const float4*)(Wg);
  float4 w_pf1 = *(const float4*)(Wg + 4);
  float4 w_pf2 = *(const float4*)(Wg + 8);
  float4 w_pf3 = *(const float4*)(Wg + 12);

  for (int k0 = 0; k0 < Kc; k0 += BK) {
    const uint4 sa0 = a_pf0, sa1 = a_pf1;
    uint4 qb0, qb1;
    qb0.x = pk2(w_pf0.x, w_pf0.y); qb0.y = pk2(w_pf0.z, w_pf0.w);
    qb0.z = pk2(w_pf1.x, w_pf1.y); qb0.w = pk2(w_pf1.z, w_pf1.w);
    qb1.x = pk2(w_pf2.x, w_pf2.y); qb1.y = pk2(w_pf2.z, w_pf2.w);
    qb1.z = pk2(w_pf3.x, w_pf3.y); qb1.w = pk2(w_pf3.z, w_pf3.w);

    __syncthreads();                       // prev iter's frag reads done
    *(uint4*)&As[ar * LDA + ak]     = sa0;
    *(uint4*)&As[ar * LDA + ak + 8] = sa1;
    *(uint4*)&Bs[ar * LDA + ak]     = qb0;
    *(uint4*)&Bs[ar * LDA + ak + 8] = qb1;
    __syncthreads();                       // staging visible

    // issue next tile's global loads NOW (overlap with ds_read+MFMA below)
    if (k0 + BK < Kc) {
      a_pf0 = *(const uint4*)(Ag + k0 + BK);
      a_pf1 = *(const uint4*)(Ag + k0 + BK + 8);
      w_pf0 = *(const float4*)(Wg + k0 + BK);
      w_pf1 = *(const float4*)(Wg + k0 + BK + 4);
      w_pf2 = *(const float4*)(Wg + k0 + BK + 8);
      w_pf3 = *(const float4*)(Wg + k0 + BK + 12);
    }

    bf16x8_t af[4], bfr[4];
    #pragma unroll
    for (int i = 0; i < 4; ++i)
      af[i] = *(const bf16x8_t*)&As[(wm + i * 16 + lrow) * LDA + lq * 8];
    #pragma unroll
    for (int j = 0; j < 4; ++j)
      bfr[j] = *(const bf16x8_t*)&Bs[(wn + j * 16 + lrow) * LDA + lq * 8];
    #pragma unroll
    for (int i = 0; i < 4; ++i)
      #pragma unroll
      for (int j = 0; j < 4; ++j)
        acc[i][j] = __builtin_amdgcn_mfma_f32_16x16x32_bf16(af[i], bfr[j], acc[i][j], 0, 0, 0);
  }

  // epilogue: C/D layout col=lane&15, row=(lane>>4)*4+r
  float bj[4];
  #pragma unroll
  for (int j = 0; j < 4; ++j)
    bj[j] = (bias && (SPLIT == 1 || blockIdx.z == 0)) ? bias[n0 + wn + j * 16 + lrow] : 0.f;
  #pragma unroll
  for (int i = 0; i < 4; ++i) {
    #pragma unroll
    for (int r = 0; r < 4; ++r) {
      const int row = m0 + wm + i * 16 + lq * 4 + r;
      const size_t idx = (size_t)row * N + n0 + wn + lrow;
      #pragma unroll
      for (int j = 0; j < 4; ++j) {
        float val = acc[i][j][r] + bj[j];
        if (GELU)
          val = 0.5f * val * (1.0f + erff(val * 0.70710678118654752f));
        if (ATOMIC)
          atomicAdd(&((float*)Cout)[idx + j * 16], val);
        else if (OUTBF16)
          ((unsigned short*)Cout)[idx + j * 16] = f2bf(val);
        else
          ((float*)Cout)[idx + j * 16] = val;
      }
    }
  }
}

// ---------------------------------------------------------------------------
// RoPE + split + transpose, bf16 out:
//   qt,kt: (B,H,S,64);  vt: (B,H,64,S)  (transposed for PV MFMA B-operand).
// ---------------------------------------------------------------------------
__global__ __launch_bounds__(256) void rope_kernel(const float* __restrict__ qkv,
    const float* __restrict__ rot, unsigned short* __restrict__ qt,
    unsigned short* __restrict__ kt, unsigned short* __restrict__ vt) {
  const int idx = blockIdx.x * 256 + threadIdx.x;   // over S*B*H*HD = 2M
  const int d  = idx & 63;
  const int hh = (idx >> 6) & 15;
  const int m  = idx >> 10;        // s*B+b
  const int s  = m >> 1;
  const int b  = m & 1;
  const float f  = rot[s * 32 + (d & 31)];
  const float cs = cosf(f);
  const float sn = sinf(f);
  const float sign = (d < 32) ? -1.0f : 1.0f;
  const size_t base  = (size_t)m * 3072 + hh * 64;
  const int bh = b * 16 + hh;
  const size_t obase = (((size_t)bh * 1024 + s) << 6) + d;
  float qv = qkv[base + d];
  float qp = qkv[base + (d ^ 32)];
  qt[obase] = f2bf(qv * cs + sign * qp * sn);
  float kv = qkv[base + 1024 + d];
  float kp = qkv[base + 1024 + (d ^ 32)];
  kt[obase] = f2bf(kv * cs + sign * kp * sn);
  vt[(((size_t)bh * 64 + d) << 10) + s] = f2bf(qkv[base + 2048 + d]);
}

// ---------------------------------------------------------------------------
// MFMA flash attention. Block = 4 waves, 64 queries (16 per wave), one bh.
// ---------------------------------------------------------------------------
__global__ __launch_bounds__(256, 2) void attn_kernel(
    const unsigned short* __restrict__ q, const unsigned short* __restrict__ k,
    const unsigned short* __restrict__ vtr, unsigned short* __restrict__ o) {
  const int tid  = threadIdx.x;
  const int wid  = tid >> 6;
  const int lane = tid & 63;
  const int col  = lane & 15;
  const int quad = lane >> 4;
  const int bh   = blockIdx.x >> 4;
  const int qw   = (blockIdx.x & 15) * 64 + wid * 16;

  __shared__ __align__(16) unsigned short Ks[64 * 72];
  __shared__ __align__(16) unsigned short Vs[64 * 72];
  __shared__ __align__(16) unsigned short Pl_[4][16 * 72];
  unsigned short* Pl = Pl_[wid];

  const unsigned short* kb = k   + ((size_t)bh << 16);
  const unsigned short* vb = vtr + ((size_t)bh << 16);

  bf16x8_t qa0, qa1;
  {
    const unsigned short* qp = q + ((((size_t)bh << 10) + qw + col) << 6) + quad * 8;
    qa0 = *(const bf16x8_t*)(qp);
    qa1 = *(const bf16x8_t*)(qp + 32);
  }

  f32x4_t oacc[4];
  #pragma unroll
  for (int j = 0; j < 4; ++j) oacc[j] = (f32x4_t){0.f, 0.f, 0.f, 0.f};
  float mr[4] = {-3.0e38f, -3.0e38f, -3.0e38f, -3.0e38f};
  float lr[4] = {0.f, 0.f, 0.f, 0.f};

  const int srow = tid >> 2;
  const int scol = (tid & 3) * 16;

  for (int t0 = 0; t0 < 1024; t0 += 64) {
    __syncthreads();
    {
      const unsigned short* gk = kb + (size_t)(t0 + srow) * 64 + scol;
      const unsigned short* gv = vb + (size_t)srow * 1024 + t0 + scol;
      uint4 ka = *(const uint4*)(gk);
      uint4 kc = *(const uint4*)(gk + 8);
      uint4 va = *(const uint4*)(gv);
      uint4 vc = *(const uint4*)(gv + 8);
      *(uint4*)&Ks[srow * 72 + scol]     = ka;
      *(uint4*)&Ks[srow * 72 + scol + 8] = kc;
      *(uint4*)&Vs[srow * 72 + scol]     = va;
      *(uint4*)&Vs[srow * 72 + scol + 8] = vc;
    }
    __syncthreads();

    f32x4_t sc[4];
    #pragma unroll
    for (int j = 0; j < 4; ++j) {
      bf16x8_t kf0 = *(const bf16x8_t*)&Ks[(j * 16 + col) * 72 + quad * 8];
      bf16x8_t kf1 = *(const bf16x8_t*)&Ks[(j * 16 + col) * 72 + quad * 8 + 32];
      f32x4_t c = (f32x4_t){0.f, 0.f, 0.f, 0.f};
      c = __builtin_amdgcn_mfma_f32_16x16x32_bf16(qa0, kf0, c, 0, 0, 0);
      c = __builtin_amdgcn_mfma_f32_16x16x32_bf16(qa1, kf1, c, 0, 0, 0);
      sc[j] = c;
    }

    #pragma unroll
    for (int r = 0; r < 4; ++r) {
      float s0 = sc[0][r] * 0.125f, s1 = sc[1][r] * 0.125f;
      float s2 = sc[2][r] * 0.125f, s3 = sc[3][r] * 0.125f;
      float rm = fmaxf(fmaxf(s0, s1), fmaxf(s2, s3));
      rm = fmaxf(rm, __shfl_xor(rm, 1));
      rm = fmaxf(rm, __shfl_xor(rm, 2));
      rm = fmaxf(rm, __shfl_xor(rm, 4));
      rm = fmaxf(rm, __shfl_xor(rm, 8));
      const float mn = fmaxf(mr[r], rm);
      const float alpha = __expf(mr[r] - mn);
      mr[r] = mn;
      const float p0 = __expf(s0 - mn), p1 = __expf(s1 - mn);
      const float p2 = __expf(s2 - mn), p3 = __expf(s3 - mn);
      float rs = p0 + p1 + p2 + p3;
      rs += __shfl_xor(rs, 1);
      rs += __shfl_xor(rs, 2);
      rs += __shfl_xor(rs, 4);
      rs += __shfl_xor(rs, 8);
      lr[r] = lr[r] * alpha + rs;
      #pragma unroll
      for (int j = 0; j < 4; ++j) oacc[j][r] *= alpha;
      const int prow = (quad * 4 + r) * 72;
      Pl[prow +  0 + col] = f2bf(p0);
      Pl[prow + 16 + col] = f2bf(p1);
      Pl[prow + 32 + col] = f2bf(p2);
      Pl[prow + 48 + col] = f2bf(p3);
    }

    bf16x8_t pa0 = *(const bf16x8_t*)&Pl[col * 72 + quad * 8];
    bf16x8_t pa1 = *(const bf16x8_t*)&Pl[col * 72 + quad * 8 + 32];
    #pragma unroll
    for (int j = 0; j < 4; ++j) {
      bf16x8_t vf0 = *(const bf16x8_t*)&Vs[(j * 16 + col) * 72 + quad * 8];
      bf16x8_t vf1 = *(const bf16x8_t*)&Vs[(j * 16 + col) * 72 + quad * 8 + 32];
      oacc[j] = __builtin_amdgcn_mfma_f32_16x16x32_bf16(pa0, vf0, oacc[j], 0, 0, 0);
      oacc[j] = __builtin_amdgcn_mfma_f32_16x16x32_bf16(pa1, vf1, oacc[j], 0, 0, 0);
    }
  }

  const int b = bh >> 4, hh = bh & 15;
  #pragma unroll
  for (int r = 0; r < 4; ++r) {
    const float inv = 1.0f / lr[r];
    const int sq = qw + quad * 4 + r;
    unsigned short* orow = o + (((size_t)sq * 2 + b) << 10) + hh * 64;
    #pragma unroll
    for (int j = 0; j < 4; ++j)
      orow[j * 16 + col] = f2bf(oacc[j][r] * inv);
  }
}

// ---------------------------------------------------------------------------
// Mean over tokens: tsum[b,d] += sum_s h[s,b,d] (8 s-chunks, atomicAdd).
// ---------------------------------------------------------------------------
__global__ __launch_bounds__(256) void mean_kernel(const float* __restrict__ h,
    float* __restrict__ tsum) {
  const int idx = blockIdx.x * 256 + threadIdx.x;
  const int bd = idx & 2047;
  const int sc = idx >> 11;
  const int b = bd >> 10, d = bd & 1023;
  float sm = 0.f;
  for (int s = sc * 128; s < sc * 128 + 128; ++s)
    sm += h[(((size_t)s * 2 + b) << 10) + d];
  atomicAdd(&tsum[bd], sm);
}

// ---------------------------------------------------------------------------
// Small mat-vec: out[b,n] = sum_d in[b,d]*W[n,d] (+bias). Wave per output n.
// ---------------------------------------------------------------------------
__global__ __launch_bounds__(256) void smallmv_kernel(const float* __restrict__ in,
    const float* __restrict__ W, const float* __restrict__ bias,
    float* __restrict__ out) {
  const int lane = threadIdx.x & 63;
  const int n = blockIdx.x * 4 + (threadIdx.x >> 6);
  const int b = blockIdx.y;
  const float* wr = W + (size_t)n * 1024;
  const float* xr = in + (size_t)b * 1024;
  float sm = 0.f;
  #pragma unroll
  for (int j = 0; j < 4; ++j) {
    float4 wv = *(const float4*)(wr + lane * 4 + j * 256);
    float4 xv = *(const float4*)(xr + lane * 4 + j * 256);
    sm += wv.x * xv.x + wv.y * xv.y + wv.z * xv.z + wv.w * xv.w;
  }
  #pragma unroll
  for (int off = 32; off; off >>= 1) sm += __shfl_xor(sm, off);
  if (lane == 0) out[(size_t)b * 1024 + n] = sm + (bias ? bias[n] : 0.f);
}

// ---------------------------------------------------------------------------
// Pooling cross-attention, split-K: 512 waves, each (bh, 64-key block).
// ---------------------------------------------------------------------------
__global__ __launch_bounds__(256) void pool_attn_part(const float* __restrict__ q,
    const float* __restrict__ k, const float* __restrict__ v,
    float* __restrict__ part) {
  const int wid  = (blockIdx.x * 256 + threadIdx.x) >> 6;  // 0..511
  const int lane = threadIdx.x & 63;
  const int bh = wid >> 4, kblk = wid & 15;
  const int b = bh >> 4, hh = bh & 15;
  const float qd = q[(size_t)b * 1024 + hh * 64 + lane];
  float mx = -3.0e38f, l = 0.f, acc = 0.f;
  for (int t = kblk * 64; t < kblk * 64 + 64; ++t) {
    const size_t ro = (((size_t)t * 2 + b) << 10) + hh * 64 + lane;
    float p = qd * k[ro];
    p += __shfl_xor(p, 32); p += __shfl_xor(p, 16); p += __shfl_xor(p, 8);
    p += __shfl_xor(p, 4);  p += __shfl_xor(p, 2);  p += __shfl_xor(p, 1);
    const float sc = p * 0.125f;
    const float mn = fmaxf(mx, sc);
    const float alpha = __expf(mx - mn);
    const float w = __expf(sc - mn);
    acc = acc * alpha + w * v[ro];
    l   = l * alpha + w;
    mx  = mn;
  }
  float* pp = part + (size_t)wid * 68;
  if (lane == 0) { pp[0] = mx; pp[1] = l; }
  pp[4 + lane] = acc;
}

__global__ __launch_bounds__(256) void pool_attn_comb(const float* __restrict__ part,
    float* __restrict__ o) {
  const int wid  = (blockIdx.x * 256 + threadIdx.x) >> 6;  // 0..31 = bh
  const int lane = threadIdx.x & 63;
  const float* pb = part + (size_t)wid * 16 * 68;
  float M = -3.0e38f;
  #pragma unroll
  for (int w = 0; w < 16; ++w) M = fmaxf(M, pb[w * 68]);
  float L = 0.f, O = 0.f;
  #pragma unroll
  for (int w = 0; w < 16; ++w) {
    const float e = __expf(pb[w * 68] - M);
    L += e * pb[w * 68 + 1];
    O += e * pb[w * 68 + 4 + lane];
  }
  const int b = wid >> 4, hh = wid & 15;
  o[(size_t)b * 1024 + hh * 64 + lane] = O / L;
}

// ---------------------------------------------------------------------------
extern "C" void kernel_launch(void* const* d_in, const int* in_sizes, int n_in,
                              void* d_out, int out_size, void* d_ws, size_t ws_size,
                              hipStream_t stream) {
  (void)in_sizes; (void)n_in; (void)out_size; (void)ws_size;
  const float* x     = (const float*)d_in[0];
  const float* rot   = (const float*)d_in[1];
  const float* ln1_w = (const float*)d_in[2];
  const float* ln1_b = (const float*)d_in[3];
  const float* in_w  = (const float*)d_in[4];
  const float* in_b  = (const float*)d_in[5];
  const float* out_w = (const float*)d_in[6];
  const float* out_b = (const float*)d_in[7];
  const float* ln2_w = (const float*)d_in[8];
  const float* ln2_b = (const float*)d_in[9];
  const float* fc_w  = (const float*)d_in[10];
  const float* fc_b  = (const float*)d_in[11];
  const float* cp_w  = (const float*)d_in[12];
  const float* cp_b  = (const float*)d_in[13];
  const float* pn_q_w = (const float*)d_in[14];
  const float* pn_q_b = (const float*)d_in[15];
  const float* pn_k_w = (const float*)d_in[16];
  const float* pn_k_b = (const float*)d_in[17];
  const float* pn_v_w = (const float*)d_in[18];
  const float* pn_v_b = (const float*)d_in[19];
  const float* pq_w  = (const float*)d_in[20];
  const float* pk_w  = (const float*)d_in[21];
  const float* pv_w  = (const float*)d_in[22];
  const float* pp_w  = (const float*)d_in[23];
  const float* pp_b  = (const float*)d_in[24];

  float* ws = (float*)d_ws;
  const size_t M1 = 1u << 20;
  float* h  = ws;              // 2M fl  (S,B,D) residual stream fp32
  float* a  = ws + 2 * M1;     // LN out bf16 / xk bf16
  float* r1 = ws + 4 * M1;     // qkv fp32 (6M) / mlp bf16 / xv bf16
  float* qt = ws + 12 * M1;    // q bf16 (B,H,S,64)  | pooling scratch
  float* kt = ws + 14 * M1;    // k bf16 (B,H,S,64)  | k_pool fp32
  float* vt = ws + 16 * M1;    // v^T bf16 (B,H,64,S)| v_pool fp32
  float* o  = ws + 18 * M1;    // attn out bf16 (S,B,D)
  unsigned short* a_bf  = (unsigned short*)a;
  unsigned short* r1_bf = (unsigned short*)r1;
  unsigned short* o_bf  = (unsigned short*)o;
  unsigned short* qt_bf = (unsigned short*)qt;
  unsigned short* kt_bf = (unsigned short*)kt;
  unsigned short* vt_bf = (unsigned short*)vt;
  float* tsum  = qt;           // pooling scratch reuses qt region
  float* xq    = qt + 2048;
  float* qpool = qt + 4096;
  float* opool = qt + 6144;
  float* ppart = qt + 8192;    // 512*68 floats

  hipMemcpyAsync(h, x, 2 * M1 * sizeof(float), hipMemcpyDeviceToDevice, stream);

  for (int l = 0; l < NLAYER; ++l) {
    ln_kernel<true><<<MROWS, 256, 0, stream>>>(h, ln1_w + l * DMODEL, ln1_b + l * DMODEL, a_bf, 1.0f);
    // QKV: SPLIT=1, inline bias, fp32 out
    gemm_mfma<1, false, false, false><<<dim3(3072 / 128, MROWS / 128, 1), 256, 0, stream>>>(
        a_bf, in_w + (size_t)l * 3072 * 1024, in_b + l * 3072, r1,
        MROWS, 3072, 1024);
    rope_kernel<<<8192, 256, 0, stream>>>(r1, rot, qt_bf, kt_bf, vt_bf);
    attn_kernel<<<512, 256, 0, stream>>>(qt_bf, kt_bf, vt_bf, o_bf);
    // out-proj: SPLIT=4, atomic accumulate into h (residual comes free)
    gemm_mfma<4, false, true, false><<<dim3(1024 / 128, MROWS / 128, 4), 256, 0, stream>>>(
        o_bf, out_w + (size_t)l * 1024 * 1024, out_b + l * 1024, h,
        MROWS, 1024, 1024);
    ln_kernel<true><<<MROWS, 256, 0, stream>>>(h, ln2_w + l * DMODEL, ln2_b + l * DMODEL, a_bf, 1.0f);
    // FC + GELU: SPLIT=1, bf16 out
    gemm_mfma<1, true, false, true><<<dim3(4096 / 128, MROWS / 128, 1), 256, 0, stream>>>(
        a_bf, fc_w + (size_t)l * 4096 * 1024, fc_b + l * 4096, r1_bf,
        MROWS, 4096, 1024);
    // c_proj: SPLIT=4, atomic accumulate into h
    gemm_mfma<4, false, true, false><<<dim3(1024 / 128, MROWS / 128, 4), 256, 0, stream>>>(
        r1_bf, cp_w + (size_t)l * 1024 * 4096, cp_b + l * 1024, h,
        MROWS, 1024, 4096);
  }

  // ---- attention pooling head ----
  hipMemsetAsync(tsum, 0, 2048 * sizeof(float), stream);
  mean_kernel<<<64, 256, 0, stream>>>(h, tsum);
  ln_kernel<false><<<BATCH, 256, 0, stream>>>(tsum, pn_q_w, pn_q_b, xq, 1.0f / S_LEN);
  ln_kernel<true><<<MROWS, 256, 0, stream>>>(h, pn_k_w, pn_k_b, a_bf, 1.0f);    // xk bf16
  ln_kernel<true><<<MROWS, 256, 0, stream>>>(h, pn_v_w, pn_v_b, r1_bf, 1.0f);   // xv bf16
  smallmv_kernel<<<dim3(256, BATCH), 256, 0, stream>>>(xq, pq_w, nullptr, qpool);
  // pool k/v projections: SPLIT=4 atomic into zeroed buffers
  hipMemsetAsync(kt, 0, (size_t)MROWS * DMODEL * sizeof(float), stream);
  hipMemsetAsync(vt, 0, (size_t)MROWS * DMODEL * sizeof(float), stream);
  gemm_mfma<4, false, true, false><<<dim3(1024 / 128, MROWS / 128, 4), 256, 0, stream>>>(
      a_bf, pk_w, nullptr, kt, MROWS, 1024, 1024);   // k_pool fp32
  gemm_mfma<4, false, true, false><<<dim3(1024 / 128, MROWS / 128, 4), 256, 0, stream>>>(
      r1_bf, pv_w, nullptr, vt, MROWS, 1024, 1024);  // v_pool fp32
  pool_attn_part<<<128, 256, 0, stream>>>(qpool, kt, vt, ppart);
  pool_attn_comb<<<8, 256, 0, stream>>>(ppart, opool);
  smallmv_kernel<<<dim3(256, BATCH), 256, 0, stream>>>(opool, pp_w, pp_b, (float*)d_out);
}

// Round 6
// 1237.823 us; speedup vs baseline: 10.5011x; 1.0891x over previous
//
#include <hip/hip_runtime.h>
#include <math.h>

#define S_LEN  1024
#define BATCH  2
#define DMODEL 1024
#define NHEAD  16
#define HDIM   64
#define NLAYER 4
#define MLPD   4096
#define MROWS  (S_LEN*BATCH)   // 2048

typedef __attribute__((ext_vector_type(8))) short bf16x8_t;
typedef __attribute__((ext_vector_type(4))) float f32x4_t;

// fp32 -> bf16 round-to-nearest-even on the bit pattern
__device__ __forceinline__ unsigned short f2bf(float f) {
  union { float f; unsigned u; } c; c.f = f;
  return (unsigned short)((c.u + 0x7FFFu + ((c.u >> 16) & 1u)) >> 16);
}
__device__ __forceinline__ float bf2f(unsigned short u) {
  union { unsigned u; float f; } c; c.u = ((unsigned)u) << 16; return c.f;
}

// async global->LDS, 16B per lane. Dest must be wave-uniform base + lane*16.
__device__ __forceinline__ void gl_lds16(const unsigned short* g, unsigned short* l) {
  __builtin_amdgcn_global_load_lds(
      (const __attribute__((address_space(1))) unsigned int*)(g),
      (__attribute__((address_space(3))) unsigned int*)(l), 16, 0, 0);
}

// ---------------------------------------------------------------------------
// fp32 -> bf16 weight conversion (grid-stride by 8 elems/thread)
// ---------------------------------------------------------------------------
__global__ __launch_bounds__(256) void w2bf_kernel(const float* __restrict__ src,
    unsigned short* __restrict__ dst, int n) {
  const int i = (blockIdx.x * 256 + threadIdx.x) * 8;
  if (i >= n) return;
  float4 v0 = *(const float4*)(src + i);
  float4 v1 = *(const float4*)(src + i + 4);
  ushort4 u0, u1;
  u0.x = f2bf(v0.x); u0.y = f2bf(v0.y); u0.z = f2bf(v0.z); u0.w = f2bf(v0.w);
  u1.x = f2bf(v1.x); u1.y = f2bf(v1.y); u1.z = f2bf(v1.z); u1.w = f2bf(v1.w);
  *(ushort4*)(dst + i)     = u0;
  *(ushort4*)(dst + i + 4) = u1;
}

// ---------------------------------------------------------------------------
// LayerNorm over last dim (D=1024). One block (256 thr) per row.
// ---------------------------------------------------------------------------
template<bool BF16OUT>
__global__ __launch_bounds__(256) void ln_kernel(const float* __restrict__ x,
    const float* __restrict__ w, const float* __restrict__ b,
    void* __restrict__ out, float inscale) {
  const int row = blockIdx.x;
  const int tid = threadIdx.x;
  const float* xr = x + (size_t)row * DMODEL;
  float4 v = *(const float4*)(xr + tid * 4);
  v.x *= inscale; v.y *= inscale; v.z *= inscale; v.w *= inscale;
  float s1 = v.x + v.y + v.z + v.w;
  float s2 = v.x*v.x + v.y*v.y + v.z*v.z + v.w*v.w;
  #pragma unroll
  for (int off = 32; off; off >>= 1) {
    s1 += __shfl_xor(s1, off);
    s2 += __shfl_xor(s2, off);
  }
  __shared__ float as1[4], as2[4];
  if ((tid & 63) == 0) { as1[tid >> 6] = s1; as2[tid >> 6] = s2; }
  __syncthreads();
  s1 = as1[0] + as1[1] + as1[2] + as1[3];
  s2 = as2[0] + as2[1] + as2[2] + as2[3];
  const float mean = s1 * (1.0f / DMODEL);
  const float var  = s2 * (1.0f / DMODEL) - mean * mean;
  const float r = rsqrtf(var + 1e-5f);
  float4 wv = *(const float4*)(w + tid * 4);
  float4 bv = *(const float4*)(b + tid * 4);
  float o0 = (v.x - mean) * r * wv.x + bv.x;
  float o1 = (v.y - mean) * r * wv.y + bv.y;
  float o2 = (v.z - mean) * r * wv.z + bv.z;
  float o3 = (v.w - mean) * r * wv.w + bv.w;
  if (BF16OUT) {
    ushort4 u; u.x = f2bf(o0); u.y = f2bf(o1); u.z = f2bf(o2); u.w = f2bf(o3);
    *(ushort4*)((unsigned short*)out + (size_t)row * DMODEL + tid * 4) = u;
  } else {
    float4 ov; ov.x = o0; ov.y = o1; ov.z = o2; ov.w = o3;
    *(float4*)((float*)out + (size_t)row * DMODEL + tid * 4) = ov;
  }
}

// ---------------------------------------------------------------------------
// MFMA GEMM v3 (m97 structure): C[M,N] (+)= A_bf16[M,K] * W_bf16[N,K]^T.
// 128x128 tile, BK=32, 4 waves 2x2. Unpadded 128x32 LDS tiles staged via
// global_load_lds width=16 (async, no VGPR round-trip). XCD swizzle: flat
// block id f -> xcd=f&7 owns n-strips {xcd, xcd+8,...} over all m, so the
// W strip stays resident in that XCD's L2. SPLIT-K via grid.z (atomicAdd).
// ---------------------------------------------------------------------------
template<int SPLIT, bool GELU, bool ATOMIC, bool OUTBF16>
__global__ __launch_bounds__(256, 3) void gemm_mfma(
    const unsigned short* __restrict__ A, const unsigned short* __restrict__ W,
    const float* __restrict__ bias, void* __restrict__ Cout,
    int M, int N, int K) {
  constexpr int BK = 32;
  __shared__ __align__(16) unsigned short As[128 * BK];
  __shared__ __align__(16) unsigned short Bs[128 * BK];
  const int tid  = threadIdx.x;
  const int wid  = tid >> 6;
  const int lane = tid & 63;
  const int lrow = lane & 15;
  const int lq   = lane >> 4;

  // XCD-aware swizzle (requires gridDim.x % 8 == 0)
  const int NB = gridDim.x, MB = gridDim.y;
  const int f = blockIdx.y * NB + blockIdx.x;
  const int xcd = f & 7;
  const int idx = f >> 3;
  const int m0 = (idx % MB) * 128;
  const int n0 = (xcd + (idx / MB) * 8) * 128;

  const int wm = (wid >> 1) * 64;
  const int wn = (wid & 1) * 64;
  const int Kc = K / SPLIT;
  const int kbase = blockIdx.z * Kc;

  f32x4_t acc[4][4];
  #pragma unroll
  for (int i = 0; i < 4; ++i)
    #pragma unroll
    for (int j = 0; j < 4; ++j) acc[i][j] = (f32x4_t){0.f, 0.f, 0.f, 0.f};

  // staging chunks: chunk c covers row c>>2, k-offset (c&3)*8 (16B)
  const int c1 = tid, c2 = tid + 256;
  const unsigned short* Ag1 = A + (size_t)(m0 + (c1 >> 2)) * K + kbase + (c1 & 3) * 8;
  const unsigned short* Ag2 = A + (size_t)(m0 + (c2 >> 2)) * K + kbase + (c2 & 3) * 8;
  const unsigned short* Wg1 = W + (size_t)(n0 + (c1 >> 2)) * K + kbase + (c1 & 3) * 8;
  const unsigned short* Wg2 = W + (size_t)(n0 + (c2 >> 2)) * K + kbase + (c2 & 3) * 8;
  unsigned short* Al1 = &As[c1 * 8];
  unsigned short* Al2 = &As[c2 * 8];
  unsigned short* Bl1 = &Bs[c1 * 8];
  unsigned short* Bl2 = &Bs[c2 * 8];

  for (int k0 = 0; k0 < Kc; k0 += BK) {
    __syncthreads();                 // prev iter's frag reads complete
    gl_lds16(Ag1 + k0, Al1);
    gl_lds16(Ag2 + k0, Al2);
    gl_lds16(Wg1 + k0, Bl1);
    gl_lds16(Wg2 + k0, Bl2);
    __syncthreads();                 // vmcnt(0) drain -> staging visible

    bf16x8_t af[4], bfr[4];
    #pragma unroll
    for (int i = 0; i < 4; ++i)
      af[i] = *(const bf16x8_t*)&As[(wm + i * 16 + lrow) * BK + lq * 8];
    #pragma unroll
    for (int j = 0; j < 4; ++j)
      bfr[j] = *(const bf16x8_t*)&Bs[(wn + j * 16 + lrow) * BK + lq * 8];
    #pragma unroll
    for (int i = 0; i < 4; ++i)
      #pragma unroll
      for (int j = 0; j < 4; ++j)
        acc[i][j] = __builtin_amdgcn_mfma_f32_16x16x32_bf16(af[i], bfr[j], acc[i][j], 0, 0, 0);
  }

  // epilogue: C/D layout col=lane&15, row=(lane>>4)*4+r
  float bj[4];
  #pragma unroll
  for (int j = 0; j < 4; ++j)
    bj[j] = (bias && (SPLIT == 1 || blockIdx.z == 0)) ? bias[n0 + wn + j * 16 + lrow] : 0.f;
  #pragma unroll
  for (int i = 0; i < 4; ++i) {
    #pragma unroll
    for (int r = 0; r < 4; ++r) {
      const int row = m0 + wm + i * 16 + lq * 4 + r;
      const size_t idx2 = (size_t)row * N + n0 + wn + lrow;
      #pragma unroll
      for (int j = 0; j < 4; ++j) {
        float val = acc[i][j][r] + bj[j];
        if (GELU)
          val = 0.5f * val * (1.0f + erff(val * 0.70710678118654752f));
        if (ATOMIC)
          atomicAdd(&((float*)Cout)[idx2 + j * 16], val);
        else if (OUTBF16)
          ((unsigned short*)Cout)[idx2 + j * 16] = f2bf(val);
        else
          ((float*)Cout)[idx2 + j * 16] = val;
      }
    }
  }
}

// ---------------------------------------------------------------------------
// RoPE + split + transpose, bf16 in (qkv) / bf16 out:
//   qt,kt: (B,H,S,64);  vt: (B,H,64,S)  (transposed for PV MFMA B-operand).
// ---------------------------------------------------------------------------
__global__ __launch_bounds__(256) void rope_kernel(const unsigned short* __restrict__ qkv,
    const float* __restrict__ rot, unsigned short* __restrict__ qt,
    unsigned short* __restrict__ kt, unsigned short* __restrict__ vt) {
  const int idx = blockIdx.x * 256 + threadIdx.x;   // over S*B*H*HD = 2M
  const int d  = idx & 63;
  const int hh = (idx >> 6) & 15;
  const int m  = idx >> 10;        // s*B+b
  const int s  = m >> 1;
  const int b  = m & 1;
  const float f  = rot[s * 32 + (d & 31)];
  const float cs = cosf(f);
  const float sn = sinf(f);
  const float sign = (d < 32) ? -1.0f : 1.0f;
  const size_t base  = (size_t)m * 3072 + hh * 64;
  const int bh = b * 16 + hh;
  const size_t obase = (((size_t)bh * 1024 + s) << 6) + d;
  float qv = bf2f(qkv[base + d]);
  float qp = bf2f(qkv[base + (d ^ 32)]);
  qt[obase] = f2bf(qv * cs + sign * qp * sn);
  float kv = bf2f(qkv[base + 1024 + d]);
  float kp = bf2f(qkv[base + 1024 + (d ^ 32)]);
  kt[obase] = f2bf(kv * cs + sign * kp * sn);
  vt[(((size_t)bh * 64 + d) << 10) + s] = qkv[base + 2048 + d];
}

// ---------------------------------------------------------------------------
// MFMA flash attention. Block = 4 waves, 64 queries (16 per wave), one bh.
// ---------------------------------------------------------------------------
__global__ __launch_bounds__(256, 2) void attn_kernel(
    const unsigned short* __restrict__ q, const unsigned short* __restrict__ k,
    const unsigned short* __restrict__ vtr, unsigned short* __restrict__ o) {
  const int tid  = threadIdx.x;
  const int wid  = tid >> 6;
  const int lane = tid & 63;
  const int col  = lane & 15;
  const int quad = lane >> 4;
  const int bh   = blockIdx.x >> 4;
  const int qw   = (blockIdx.x & 15) * 64 + wid * 16;

  __shared__ __align__(16) unsigned short Ks[64 * 72];
  __shared__ __align__(16) unsigned short Vs[64 * 72];
  __shared__ __align__(16) unsigned short Pl_[4][16 * 72];
  unsigned short* Pl = Pl_[wid];

  const unsigned short* kb = k   + ((size_t)bh << 16);
  const unsigned short* vb = vtr + ((size_t)bh << 16);

  bf16x8_t qa0, qa1;
  {
    const unsigned short* qp = q + ((((size_t)bh << 10) + qw + col) << 6) + quad * 8;
    qa0 = *(const bf16x8_t*)(qp);
    qa1 = *(const bf16x8_t*)(qp + 32);
  }

  f32x4_t oacc[4];
  #pragma unroll
  for (int j = 0; j < 4; ++j) oacc[j] = (f32x4_t){0.f, 0.f, 0.f, 0.f};
  float mr[4] = {-3.0e38f, -3.0e38f, -3.0e38f, -3.0e38f};
  float lr[4] = {0.f, 0.f, 0.f, 0.f};

  const int srow = tid >> 2;
  const int scol = (tid & 3) * 16;

  for (int t0 = 0; t0 < 1024; t0 += 64) {
    __syncthreads();
    {
      const unsigned short* gk = kb + (size_t)(t0 + srow) * 64 + scol;
      const unsigned short* gv = vb + (size_t)srow * 1024 + t0 + scol;
      uint4 ka = *(const uint4*)(gk);
      uint4 kc = *(const uint4*)(gk + 8);
      uint4 va = *(const uint4*)(gv);
      uint4 vc = *(const uint4*)(gv + 8);
      *(uint4*)&Ks[srow * 72 + scol]     = ka;
      *(uint4*)&Ks[srow * 72 + scol + 8] = kc;
      *(uint4*)&Vs[srow * 72 + scol]     = va;
      *(uint4*)&Vs[srow * 72 + scol + 8] = vc;
    }
    __syncthreads();

    f32x4_t sc[4];
    #pragma unroll
    for (int j = 0; j < 4; ++j) {
      bf16x8_t kf0 = *(const bf16x8_t*)&Ks[(j * 16 + col) * 72 + quad * 8];
      bf16x8_t kf1 = *(const bf16x8_t*)&Ks[(j * 16 + col) * 72 + quad * 8 + 32];
      f32x4_t c = (f32x4_t){0.f, 0.f, 0.f, 0.f};
      c = __builtin_amdgcn_mfma_f32_16x16x32_bf16(qa0, kf0, c, 0, 0, 0);
      c = __builtin_amdgcn_mfma_f32_16x16x32_bf16(qa1, kf1, c, 0, 0, 0);
      sc[j] = c;
    }

    #pragma unroll
    for (int r = 0; r < 4; ++r) {
      float s0 = sc[0][r] * 0.125f, s1 = sc[1][r] * 0.125f;
      float s2 = sc[2][r] * 0.125f, s3 = sc[3][r] * 0.125f;
      float rm = fmaxf(fmaxf(s0, s1), fmaxf(s2, s3));
      rm = fmaxf(rm, __shfl_xor(rm, 1));
      rm = fmaxf(rm, __shfl_xor(rm, 2));
      rm = fmaxf(rm, __shfl_xor(rm, 4));
      rm = fmaxf(rm, __shfl_xor(rm, 8));
      const float mn = fmaxf(mr[r], rm);
      const float alpha = __expf(mr[r] - mn);
      mr[r] = mn;
      const float p0 = __expf(s0 - mn), p1 = __expf(s1 - mn);
      const float p2 = __expf(s2 - mn), p3 = __expf(s3 - mn);
      float rs = p0 + p1 + p2 + p3;
      rs += __shfl_xor(rs, 1);
      rs += __shfl_xor(rs, 2);
      rs += __shfl_xor(rs, 4);
      rs += __shfl_xor(rs, 8);
      lr[r] = lr[r] * alpha + rs;
      #pragma unroll
      for (int j = 0; j < 4; ++j) oacc[j][r] *= alpha;
      const int prow = (quad * 4 + r) * 72;
      Pl[prow +  0 + col] = f2bf(p0);
      Pl[prow + 16 + col] = f2bf(p1);
      Pl[prow + 32 + col] = f2bf(p2);
      Pl[prow + 48 + col] = f2bf(p3);
    }

    bf16x8_t pa0 = *(const bf16x8_t*)&Pl[col * 72 + quad * 8];
    bf16x8_t pa1 = *(const bf16x8_t*)&Pl[col * 72 + quad * 8 + 32];
    #pragma unroll
    for (int j = 0; j < 4; ++j) {
      bf16x8_t vf0 = *(const bf16x8_t*)&Vs[(j * 16 + col) * 72 + quad * 8];
      bf16x8_t vf1 = *(const bf16x8_t*)&Vs[(j * 16 + col) * 72 + quad * 8 + 32];
      oacc[j] = __builtin_amdgcn_mfma_f32_16x16x32_bf16(pa0, vf0, oacc[j], 0, 0, 0);
      oacc[j] = __builtin_amdgcn_mfma_f32_16x16x32_bf16(pa1, vf1, oacc[j], 0, 0, 0);
    }
  }

  const int b = bh >> 4, hh = bh & 15;
  #pragma unroll
  for (int r = 0; r < 4; ++r) {
    const float inv = 1.0f / lr[r];
    const int sq = qw + quad * 4 + r;
    unsigned short* orow = o + (((size_t)sq * 2 + b) << 10) + hh * 64;
    #pragma unroll
    for (int j = 0; j < 4; ++j)
      orow[j * 16 + col] = f2bf(oacc[j][r] * inv);
  }
}

// ---------------------------------------------------------------------------
// Mean over tokens: tsum[b,d] += sum_s h[s,b,d] (8 s-chunks, atomicAdd).
// ---------------------------------------------------------------------------
__global__ __launch_bounds__(256) void mean_kernel(const float* __restrict__ h,
    float* __restrict__ tsum) {
  const int idx = blockIdx.x * 256 + threadIdx.x;
  const int bd = idx & 2047;
  const int sc = idx >> 11;
  const int b = bd >> 10, d = bd & 1023;
  float sm = 0.f;
  for (int s = sc * 128; s < sc * 128 + 128; ++s)
    sm += h[(((size_t)s * 2 + b) << 10) + d];
  atomicAdd(&tsum[bd], sm);
}

// ---------------------------------------------------------------------------
// Small mat-vec: out[b,n] = sum_d in[b,d]*W[n,d] (+bias). Wave per output n.
// ---------------------------------------------------------------------------
__global__ __launch_bounds__(256) void smallmv_kernel(const float* __restrict__ in,
    const float* __restrict__ W, const float* __restrict__ bias,
    float* __restrict__ out) {
  const int lane = threadIdx.x & 63;
  const int n = blockIdx.x * 4 + (threadIdx.x >> 6);
  const int b = blockIdx.y;
  const float* wr = W + (size_t)n * 1024;
  const float* xr = in + (size_t)b * 1024;
  float sm = 0.f;
  #pragma unroll
  for (int j = 0; j < 4; ++j) {
    float4 wv = *(const float4*)(wr + lane * 4 + j * 256);
    float4 xv = *(const float4*)(xr + lane * 4 + j * 256);
    sm += wv.x * xv.x + wv.y * xv.y + wv.z * xv.z + wv.w * xv.w;
  }
  #pragma unroll
  for (int off = 32; off; off >>= 1) sm += __shfl_xor(sm, off);
  if (lane == 0) out[(size_t)b * 1024 + n] = sm + (bias ? bias[n] : 0.f);
}

// ---------------------------------------------------------------------------
// Pooling cross-attention, split-K: 512 waves, each (bh, 64-key block).
// ---------------------------------------------------------------------------
__global__ __launch_bounds__(256) void pool_attn_part(const float* __restrict__ q,
    const float* __restrict__ k, const float* __restrict__ v,
    float* __restrict__ part) {
  const int wid  = (blockIdx.x * 256 + threadIdx.x) >> 6;  // 0..511
  const int lane = threadIdx.x & 63;
  const int bh = wid >> 4, kblk = wid & 15;
  const int b = bh >> 4, hh = bh & 15;
  const float qd = q[(size_t)b * 1024 + hh * 64 + lane];
  float mx = -3.0e38f, l = 0.f, acc = 0.f;
  for (int t = kblk * 64; t < kblk * 64 + 64; ++t) {
    const size_t ro = (((size_t)t * 2 + b) << 10) + hh * 64 + lane;
    float p = qd * k[ro];
    p += __shfl_xor(p, 32); p += __shfl_xor(p, 16); p += __shfl_xor(p, 8);
    p += __shfl_xor(p, 4);  p += __shfl_xor(p, 2);  p += __shfl_xor(p, 1);
    const float sc = p * 0.125f;
    const float mn = fmaxf(mx, sc);
    const float alpha = __expf(mx - mn);
    const float w = __expf(sc - mn);
    acc = acc * alpha + w * v[ro];
    l   = l * alpha + w;
    mx  = mn;
  }
  float* pp = part + (size_t)wid * 68;
  if (lane == 0) { pp[0] = mx; pp[1] = l; }
  pp[4 + lane] = acc;
}

__global__ __launch_bounds__(256) void pool_attn_comb(const float* __restrict__ part,
    float* __restrict__ o) {
  const int wid  = (blockIdx.x * 256 + threadIdx.x) >> 6;  // 0..31 = bh
  const int lane = threadIdx.x & 63;
  const float* pb = part + (size_t)wid * 16 * 68;
  float M = -3.0e38f;
  #pragma unroll
  for (int w = 0; w < 16; ++w) M = fmaxf(M, pb[w * 68]);
  float L = 0.f, O = 0.f;
  #pragma unroll
  for (int w = 0; w < 16; ++w) {
    const float e = __expf(pb[w * 68] - M);
    L += e * pb[w * 68 + 1];
    O += e * pb[w * 68 + 4 + lane];
  }
  const int b = wid >> 4, hh = wid & 15;
  o[(size_t)b * 1024 + hh * 64 + lane] = O / L;
}

// ---------------------------------------------------------------------------
extern "C" void kernel_launch(void* const* d_in, const int* in_sizes, int n_in,
                              void* d_out, int out_size, void* d_ws, size_t ws_size,
                              hipStream_t stream) {
  (void)in_sizes; (void)n_in; (void)out_size; (void)ws_size;
  const float* x     = (const float*)d_in[0];
  const float* rot   = (const float*)d_in[1];
  const float* ln1_w = (const float*)d_in[2];
  const float* ln1_b = (const float*)d_in[3];
  const float* in_w  = (const float*)d_in[4];
  const float* in_b  = (const float*)d_in[5];
  const float* out_w = (const float*)d_in[6];
  const float* out_b = (const float*)d_in[7];
  const float* ln2_w = (const float*)d_in[8];
  const float* ln2_b = (const float*)d_in[9];
  const float* fc_w  = (const float*)d_in[10];
  const float* fc_b  = (const float*)d_in[11];
  const float* cp_w  = (const float*)d_in[12];
  const float* cp_b  = (const float*)d_in[13];
  const float* pn_q_w = (const float*)d_in[14];
  const float* pn_q_b = (const float*)d_in[15];
  const float* pn_k_w = (const float*)d_in[16];
  const float* pn_k_b = (const float*)d_in[17];
  const float* pn_v_w = (const float*)d_in[18];
  const float* pn_v_b = (const float*)d_in[19];
  const float* pq_w  = (const float*)d_in[20];
  const float* pk_w  = (const float*)d_in[21];
  const float* pv_w  = (const float*)d_in[22];
  const float* pp_w  = (const float*)d_in[23];
  const float* pp_b  = (const float*)d_in[24];

  float* ws = (float*)d_ws;
  const size_t M1 = 1u << 20;
  float* h  = ws;              // 2M fl  (S,B,D) residual stream fp32
  float* a  = ws + 2 * M1;     // LN out bf16 / xk bf16
  float* r1 = ws + 4 * M1;     // qkv bf16 / mlp bf16 / xv bf16
  float* qt = ws + 12 * M1;    // q bf16 (B,H,S,64)  | pooling scratch
  float* kt = ws + 14 * M1;    // k bf16 (B,H,S,64)  | k_pool fp32
  float* vt = ws + 16 * M1;    // v^T bf16 (B,H,64,S)| v_pool fp32
  float* o  = ws + 18 * M1;    // attn out bf16 (S,B,D)
  float* wbf = ws + 20 * M1;   // bf16 weights for current layer (6.3M fl)
  unsigned short* a_bf  = (unsigned short*)a;
  unsigned short* r1_bf = (unsigned short*)r1;
  unsigned short* o_bf  = (unsigned short*)o;
  unsigned short* qt_bf = (unsigned short*)qt;
  unsigned short* kt_bf = (unsigned short*)kt;
  unsigned short* vt_bf = (unsigned short*)vt;
  // bf16 weight partitions (ushort elems)
  unsigned short* wb_qkv = (unsigned short*)wbf;            // 3,145,728
  unsigned short* wb_out = wb_qkv + 3145728;                // 1,048,576
  unsigned short* wb_fc  = wb_out + 1048576;                // 4,194,304
  unsigned short* wb_cp  = wb_fc  + 4194304;                // 4,194,304
  float* tsum  = qt;           // pooling scratch reuses qt region
  float* xq    = qt + 2048;
  float* qpool = qt + 4096;
  float* opool = qt + 6144;
  float* ppart = qt + 8192;    // 512*68 floats

  hipMemcpyAsync(h, x, 2 * M1 * sizeof(float), hipMemcpyDeviceToDevice, stream);

  for (int l = 0; l < NLAYER; ++l) {
    // weight conversion for this layer (BW-bound, ~12 us)
    w2bf_kernel<<<3145728 / 2048, 256, 0, stream>>>(in_w + (size_t)l * 3145728, wb_qkv, 3145728);
    w2bf_kernel<<<1048576 / 2048, 256, 0, stream>>>(out_w + (size_t)l * 1048576, wb_out, 1048576);
    w2bf_kernel<<<4194304 / 2048, 256, 0, stream>>>(fc_w + (size_t)l * 4194304, wb_fc, 4194304);
    w2bf_kernel<<<4194304 / 2048, 256, 0, stream>>>(cp_w + (size_t)l * 4194304, wb_cp, 4194304);

    ln_kernel<true><<<MROWS, 256, 0, stream>>>(h, ln1_w + l * DMODEL, ln1_b + l * DMODEL, a_bf, 1.0f);
    // QKV: SPLIT=1, inline bias, bf16 out
    gemm_mfma<1, false, false, true><<<dim3(3072 / 128, MROWS / 128, 1), 256, 0, stream>>>(
        a_bf, wb_qkv, in_b + l * 3072, r1_bf, MROWS, 3072, 1024);
    rope_kernel<<<8192, 256, 0, stream>>>(r1_bf, rot, qt_bf, kt_bf, vt_bf);
    attn_kernel<<<512, 256, 0, stream>>>(qt_bf, kt_bf, vt_bf, o_bf);
    // out-proj: SPLIT=4, atomic accumulate into h (residual comes free)
    gemm_mfma<4, false, true, false><<<dim3(1024 / 128, MROWS / 128, 4), 256, 0, stream>>>(
        o_bf, wb_out, out_b + l * 1024, h, MROWS, 1024, 1024);
    ln_kernel<true><<<MROWS, 256, 0, stream>>>(h, ln2_w + l * DMODEL, ln2_b + l * DMODEL, a_bf, 1.0f);
    // FC + GELU: SPLIT=1, bf16 out
    gemm_mfma<1, true, false, true><<<dim3(4096 / 128, MROWS / 128, 1), 256, 0, stream>>>(
        a_bf, wb_fc, fc_b + l * 4096, r1_bf, MROWS, 4096, 1024);
    // c_proj: SPLIT=4, atomic accumulate into h
    gemm_mfma<4, false, true, false><<<dim3(1024 / 128, MROWS / 128, 4), 256, 0, stream>>>(
        r1_bf, wb_cp, cp_b + l * 1024, h, MROWS, 1024, 4096);
  }

  // ---- attention pooling head ----
  hipMemsetAsync(tsum, 0, 2048 * sizeof(float), stream);
  mean_kernel<<<64, 256, 0, stream>>>(h, tsum);
  ln_kernel<false><<<BATCH, 256, 0, stream>>>(tsum, pn_q_w, pn_q_b, xq, 1.0f / S_LEN);
  ln_kernel<true><<<MROWS, 256, 0, stream>>>(h, pn_k_w, pn_k_b, a_bf, 1.0f);    // xk bf16
  ln_kernel<true><<<MROWS, 256, 0, stream>>>(h, pn_v_w, pn_v_b, r1_bf, 1.0f);   // xv bf16
  smallmv_kernel<<<dim3(256, BATCH), 256, 0, stream>>>(xq, pq_w, nullptr, qpool);
  // pool k/v projections: bf16 weights, SPLIT=4 atomic into zeroed buffers
  w2bf_kernel<<<1048576 / 2048, 256, 0, stream>>>(pk_w, wb_qkv, 1048576);
  w2bf_kernel<<<1048576 / 2048, 256, 0, stream>>>(pv_w, wb_out, 1048576);
  hipMemsetAsync(kt, 0, (size_t)MROWS * DMODEL * sizeof(float), stream);
  hipMemsetAsync(vt, 0, (size_t)MROWS * DMODEL * sizeof(float), stream);
  gemm_mfma<4, false, true, false><<<dim3(1024 / 128, MROWS / 128, 4), 256, 0, stream>>>(
      a_bf, wb_qkv, nullptr, kt, MROWS, 1024, 1024);   // k_pool fp32
  gemm_mfma<4, false, true, false><<<dim3(1024 / 128, MROWS / 128, 4), 256, 0, stream>>>(
      r1_bf, wb_out, nullptr, vt, MROWS, 1024, 1024);  // v_pool fp32
  pool_attn_part<<<128, 256, 0, stream>>>(qpool, kt, vt, ppart);
  pool_attn_comb<<<8, 256, 0, stream>>>(ppart, opool);
  smallmv_kernel<<<dim3(256, BATCH), 256, 0, stream>>>(opool, pp_w, pp_b, (float*)d_out);
}